// Round 1
// baseline (953.719 us; speedup 1.0000x reference)
//
#include <hip/hip_runtime.h>
#include <math.h>

#define D   128
#define NH  8
#define DKD 16
#define FFD 512

static inline size_t align256(size_t x){ return (x + 255) & ~(size_t)255; }

// ---------------- CSR build ----------------
__global__ __launch_bounds__(256) void k_count(const int* __restrict__ dst, int E,
                                               int* __restrict__ cnt){
    int i = blockIdx.x*blockDim.x + threadIdx.x;
    int stride = gridDim.x*blockDim.x;
    for (; i < E; i += stride) atomicAdd(&cnt[dst[i]], 1);
}

__global__ __launch_bounds__(1024) void k_scan(const int* __restrict__ cnt, int N,
                                               int* __restrict__ off, int* __restrict__ cur){
    __shared__ int part[1024];
    int tid = threadIdx.x;
    int chunk = (N + 1023) / 1024;
    int beg = tid*chunk, end = min(beg+chunk, N);
    if (beg > N) beg = N;
    int s = 0;
    for (int i = beg; i < end; i++) s += cnt[i];
    part[tid] = s;
    __syncthreads();
    for (int o = 1; o < 1024; o <<= 1){
        int t = (tid >= o) ? part[tid-o] : 0;
        __syncthreads();
        part[tid] += t;
        __syncthreads();
    }
    int run = part[tid] - s;          // exclusive prefix of this chunk
    for (int i = beg; i < end; i++){
        int c = cnt[i];
        off[i] = run; cur[i] = run;
        run += c;
    }
    if (tid == 1023) off[N] = part[1023];
}

__global__ __launch_bounds__(256) void k_scatter(const int* __restrict__ src,
                                                 const int* __restrict__ dst, int E,
                                                 int* __restrict__ cur,
                                                 int* __restrict__ csr_src){
    int i = blockIdx.x*blockDim.x + threadIdx.x;
    int stride = gridDim.x*blockDim.x;
    for (; i < E; i += stride){
        int p = atomicAdd(&cur[dst[i]], 1);
        csr_src[p] = src[i];
    }
}

// ---------------- generic tiled f32 GEMM: C[M,Nc] = A[M,K]@B[K,Nc] (+bias)(+relu) ----------------
__global__ __launch_bounds__(256) void k_gemm(const float* __restrict__ A,
                                              const float* __restrict__ B,
                                              float* __restrict__ C,
                                              int M, int Nc, int K,
                                              const float* __restrict__ bias, int relu){
    __shared__ float At[32][68];   // k-major (transposed) A tile, padded
    __shared__ float Bt[32][68];   // k-major B tile, padded
    int tid = threadIdx.x;
    int tc = tid & 15, tr = tid >> 4;           // 16x16 thread grid, 4x4 outputs each
    int r0 = blockIdx.x * 64, c0 = blockIdx.y * 64;
    float acc[4][4] = {};
    for (int k0 = 0; k0 < K; k0 += 32){
        #pragma unroll
        for (int i = 0; i < 8; i++){
            int idx = tid + i*256;
            int kk = idx & 31, r = idx >> 5;
            int row = r0 + r;
            At[kk][r] = (row < M) ? A[(size_t)row*K + k0 + kk] : 0.f;
        }
        #pragma unroll
        for (int i = 0; i < 8; i++){
            int idx = tid + i*256;
            int c = idx & 63, kk = idx >> 6;
            Bt[kk][c] = B[(size_t)(k0+kk)*Nc + c0 + c];
        }
        __syncthreads();
        #pragma unroll
        for (int kk = 0; kk < 32; kk++){
            float4 a4 = *(const float4*)&At[kk][tr*4];
            float4 b4 = *(const float4*)&Bt[kk][tc*4];
            const float* ap = &a4.x;
            const float* bp = &b4.x;
            #pragma unroll
            for (int i = 0; i < 4; i++)
                #pragma unroll
                for (int j = 0; j < 4; j++)
                    acc[i][j] = fmaf(ap[i], bp[j], acc[i][j]);
        }
        __syncthreads();
    }
    float4 bf4 = {0,0,0,0};
    if (bias) bf4 = *(const float4*)&bias[c0 + tc*4];
    const float* bfp = &bf4.x;
    #pragma unroll
    for (int i = 0; i < 4; i++){
        int row = r0 + tr*4 + i;
        if (row >= M) continue;
        float4 out;
        float* op = &out.x;
        #pragma unroll
        for (int j = 0; j < 4; j++){
            float v = acc[i][j] + bfp[j];
            if (relu) v = fmaxf(v, 0.f);
            op[j] = v;
        }
        *(float4*)&C[(size_t)row*Nc + c0 + tc*4] = out;
    }
}

// ---------------- per-node online-softmax attention ----------------
__global__ __launch_bounds__(256) void k_attn(const float* __restrict__ q,
                                              const float* __restrict__ k,
                                              const float* __restrict__ v,
                                              const int* __restrict__ off,
                                              const int* __restrict__ csr_src,
                                              float* __restrict__ a, int N){
    int wid = (blockIdx.x*blockDim.x + threadIdx.x) >> 6;
    int lane = threadIdx.x & 63;
    if (wid >= N) return;
    int n = wid;
    const float2 q2 = *(const float2*)&q[(size_t)n*D + lane*2];
    int beg = off[n], end = off[n+1];
    float m = -INFINITY, d = 0.f;
    float2 acc = {0.f, 0.f};
    for (int e = beg; e < end; e++){
        int s = csr_src[e];
        const float2 k2 = *(const float2*)&k[(size_t)s*D + lane*2];
        const float2 v2 = *(const float2*)&v[(size_t)s*D + lane*2];
        float p = q2.x*k2.x + q2.y*k2.y;
        p += __shfl_xor(p, 1);
        p += __shfl_xor(p, 2);
        p += __shfl_xor(p, 4);          // per-head (8-lane group) dot of 16 dims
        float es = p * 0.25f;           // 1/sqrt(16)
        float nm = fmaxf(m, es);
        float sc = __expf(m - es > 0.f ? 0.f : m - nm);   // exp(m-nm); m=-inf first iter -> 0
        sc = __expf(m - nm);
        float w  = __expf(es - nm);
        d = d*sc + w;
        acc.x = acc.x*sc + w*v2.x;
        acc.y = acc.y*sc + w*v2.y;
        m = nm;
    }
    float2 o2 = {0.f, 0.f};
    if (d > 0.f){ float r = 1.f/d; o2.x = acc.x*r; o2.y = acc.y*r; }
    *(float2*)&a[(size_t)n*D + lane*2] = o2;
}

// ---------------- fused residual + LayerNorm (row per wave) ----------------
__global__ __launch_bounds__(256) void k_ln(const float* __restrict__ x1,
                                            const float* __restrict__ x2,
                                            const float* __restrict__ g,
                                            const float* __restrict__ b,
                                            float* __restrict__ y, int N){
    int wid = (blockIdx.x*blockDim.x + threadIdx.x) >> 6;
    int lane = threadIdx.x & 63;
    if (wid >= N) return;
    float2 a_ = *(const float2*)&x1[(size_t)wid*D + lane*2];
    float2 b_ = *(const float2*)&x2[(size_t)wid*D + lane*2];
    float x0 = a_.x + b_.x, x1v = a_.y + b_.y;
    float s = x0 + x1v;
    #pragma unroll
    for (int o = 1; o < 64; o <<= 1) s += __shfl_xor(s, o);
    float mu = s * (1.f/128.f);
    float d0 = x0 - mu, d1 = x1v - mu;
    float vs = d0*d0 + d1*d1;
    #pragma unroll
    for (int o = 1; o < 64; o <<= 1) vs += __shfl_xor(vs, o);
    float inv = rsqrtf(vs*(1.f/128.f) + 1e-5f);
    float2 gg = *(const float2*)&g[lane*2];
    float2 bb = *(const float2*)&b[lane*2];
    float2 out = { d0*inv*gg.x + bb.x, d1*inv*gg.y + bb.y };
    *(float2*)&y[(size_t)wid*D + lane*2] = out;
}

extern "C" void kernel_launch(void* const* d_in, const int* in_sizes, int n_in,
                              void* d_out, int out_size, void* d_ws, size_t ws_size,
                              hipStream_t stream){
    const float* h    = (const float*)d_in[0];
    const int*   src  = (const int*)  d_in[1];
    const int*   dst  = (const int*)  d_in[2];
    const float* Wq   = (const float*)d_in[3];
    const float* Wk   = (const float*)d_in[4];
    const float* Wv   = (const float*)d_in[5];
    const float* Wo   = (const float*)d_in[6];
    const float* ln1g = (const float*)d_in[7];
    const float* ln1b = (const float*)d_in[8];
    const float* ln2g = (const float*)d_in[9];
    const float* ln2b = (const float*)d_in[10];
    const float* W1   = (const float*)d_in[11];
    const float* b1   = (const float*)d_in[12];
    const float* W2   = (const float*)d_in[13];
    const float* b2   = (const float*)d_in[14];
    float* out = (float*)d_out;

    const int N = in_sizes[0] / D;
    const int E = in_sizes[1];

    char* ws = (char*)d_ws;
    size_t o = 0;
    const size_t rowbuf = align256((size_t)N * D * sizeof(float));
    float* q   = (float*)(ws + o); o += rowbuf;
    float* k   = (float*)(ws + o); o += rowbuf;
    float* v   = (float*)(ws + o); o += rowbuf;
    float* a   = (float*)(ws + o); o += rowbuf;
    float* t1  = q;                               // N x 512 overlays q,k,v,a after attention
    float* h1  = (float*)(ws + o); o += rowbuf;
    float* tmp = (float*)(ws + o); o += rowbuf;   // o-proj, then FFN output
    int* cnt   = (int*)(ws + o); o += align256((size_t)N*4);
    int* cur   = (int*)(ws + o); o += align256((size_t)N*4);
    int* offp  = (int*)(ws + o); o += align256((size_t)(N+1)*4);
    int* csr   = (int*)(ws + o); o += align256((size_t)E*4);

    // --- CSR build ---
    hipMemsetAsync(cnt, 0, (size_t)N*4, stream);
    int eb = min((E + 255)/256, 4096);
    k_count  <<<eb, 256, 0, stream>>>(dst, E, cnt);
    k_scan   <<<1, 1024, 0, stream>>>(cnt, N, offp, cur);
    k_scatter<<<eb, 256, 0, stream>>>(src, dst, E, cur, csr);

    // --- QKV projections ---
    dim3 g128((N + 63)/64, 2);
    k_gemm<<<g128, 256, 0, stream>>>(h, Wq, q, N, D, D, nullptr, 0);
    k_gemm<<<g128, 256, 0, stream>>>(h, Wk, k, N, D, D, nullptr, 0);
    k_gemm<<<g128, 256, 0, stream>>>(h, Wv, v, N, D, D, nullptr, 0);

    // --- sparse attention ---
    int ab = (N*64 + 255)/256;
    k_attn<<<ab, 256, 0, stream>>>(q, k, v, offp, csr, a, N);

    // --- output projection + LN1 ---
    k_gemm<<<g128, 256, 0, stream>>>(a, Wo, tmp, N, D, D, nullptr, 0);
    int lb = (N*64 + 255)/256;
    k_ln<<<lb, 256, 0, stream>>>(h, tmp, ln1g, ln1b, h1, N);

    // --- FFN ---
    dim3 g512((N + 63)/64, 8);
    k_gemm<<<g512, 256, 0, stream>>>(h1, W1, t1, N, FFD, D, b1, 1);
    k_gemm<<<g128, 256, 0, stream>>>(t1, W2, tmp, N, D, FFD, b2, 0);

    // --- LN2 -> out ---
    k_ln<<<lb, 256, 0, stream>>>(h1, tmp, ln2g, ln2b, out, N);
}

// Round 3
// 597.350 us; speedup vs baseline: 1.5966x; 1.5966x over previous
//
#include <hip/hip_runtime.h>
#include <hip/hip_bf16.h>
#include <math.h>

#define D   128
#define FFD 512

typedef __attribute__((ext_vector_type(8))) short bf16x8;
typedef __attribute__((ext_vector_type(4))) float f32x4;

static inline size_t align256(size_t x){ return (x + 255) & ~(size_t)255; }

__device__ __forceinline__ float bf2f(unsigned short u){
    union { unsigned int i; float f; } x; x.i = ((unsigned int)u) << 16; return x.f;
}

__device__ __forceinline__ unsigned short f2bf(float f){
    return __builtin_bit_cast(unsigned short, __float2bfloat16(f));
}

// ---------------- CSR build ----------------
__global__ __launch_bounds__(256) void k_count(const int* __restrict__ dst, int E,
                                               int* __restrict__ cnt){
    int i = blockIdx.x*blockDim.x + threadIdx.x;
    int stride = gridDim.x*blockDim.x;
    for (; i < E; i += stride) atomicAdd(&cnt[dst[i]], 1);
}

__global__ __launch_bounds__(1024) void k_scan(const int* __restrict__ cnt, int N,
                                               int* __restrict__ off, int* __restrict__ cur){
    __shared__ int part[1024];
    int tid = threadIdx.x;
    int chunk = (N + 1023) / 1024;
    int beg = tid*chunk, end = min(beg+chunk, N);
    if (beg > N) beg = N;
    int s = 0;
    for (int i = beg; i < end; i++) s += cnt[i];
    part[tid] = s;
    __syncthreads();
    for (int o = 1; o < 1024; o <<= 1){
        int t = (tid >= o) ? part[tid-o] : 0;
        __syncthreads();
        part[tid] += t;
        __syncthreads();
    }
    int run = part[tid] - s;
    for (int i = beg; i < end; i++){
        int c = cnt[i];
        off[i] = run; cur[i] = run;
        run += c;
    }
    if (tid == 1023) off[N] = part[1023];
}

__global__ __launch_bounds__(256) void k_scatter(const int* __restrict__ src,
                                                 const int* __restrict__ dst, int E,
                                                 int* __restrict__ cur,
                                                 int* __restrict__ csr_src){
    int i = blockIdx.x*blockDim.x + threadIdx.x;
    int stride = gridDim.x*blockDim.x;
    for (; i < E; i += stride){
        int p = atomicAdd(&cur[dst[i]], 1);
        csr_src[p] = src[i];
    }
}

// ---------------- prep: cast h -> bf16 ----------------
__global__ __launch_bounds__(256) void k_cast(const float* __restrict__ x,
                                              __hip_bfloat16* __restrict__ y, int n4){
    int i = blockIdx.x*blockDim.x + threadIdx.x;
    if (i >= n4) return;
    float4 f = ((const float4*)x)[i];
    ushort4 u;
    u.x = f2bf(f.x); u.y = f2bf(f.y);
    u.z = f2bf(f.z); u.w = f2bf(f.w);
    ((ushort4*)y)[i] = u;
}

// ---------------- prep: W [K][Nc] f32 -> Wt [Nc][K] bf16 ----------------
__global__ __launch_bounds__(256) void k_prep_w(const float* __restrict__ W,
                                                __hip_bfloat16* __restrict__ Wt,
                                                int K, int Nc){
    int id = blockIdx.x*blockDim.x + threadIdx.x;
    if (id >= K*Nc) return;
    int n = id / K, kk = id % K;
    Wt[id] = __float2bfloat16(W[(size_t)kk*Nc + n]);
}

// ---------------- MFMA bf16 GEMM: C[M,Nc] = A[M,K] @ Bt[Nc,K]^T ----------------
// 128x128 tile, BK=64, 4 waves (2x2), 4x4 16x16x32 fragments per wave.
// LDS XOR swizzle (16B slot ^= row&7) applied on the GLOBAL source side
// (global_load_lds writes linearly) and on the ds_read side.
#define BM 128
#define BN 128
#define BK 64

__device__ __forceinline__ void stage_tile(const __hip_bfloat16* __restrict__ src,
                                           int row_base, int row_limit, int K, int k0,
                                           __hip_bfloat16* lds){
    int tid = threadIdx.x;
    int wave = tid >> 6;
    #pragma unroll
    for (int i = 0; i < 4; ++i){
        int c = i*256 + tid;          // 16B chunk index: 1024 chunks = 128 rows x 8 slots
        int r = c >> 3, s = c & 7;
        int sg = s ^ (r & 7);         // inverse swizzle on source
        int gr = row_base + r; if (gr >= row_limit) gr = row_limit - 1;
        const __hip_bfloat16* gp = src + (size_t)gr*K + k0 + sg*8;
        char* lp = (char*)lds + (i*256 + wave*64)*16;   // wave-uniform base
        __builtin_amdgcn_global_load_lds((const __attribute__((address_space(1))) void*)gp,
                                         (__attribute__((address_space(3))) void*)lp,
                                         16, 0, 0);
    }
}

__global__ __launch_bounds__(256) void k_mfma_gemm(
    const __hip_bfloat16* __restrict__ A,   // [M][K]
    const __hip_bfloat16* __restrict__ Bt,  // [Nc][K]
    int M, int Nc, int K, int ldc,
    const float* __restrict__ bias, int relu,
    float* __restrict__ Cf, __hip_bfloat16* __restrict__ Cb){
    __shared__ __hip_bfloat16 As[BM*BK];
    __shared__ __hip_bfloat16 Bs[BN*BK];
    int tid = threadIdx.x;
    int lane = tid & 63, wave = tid >> 6;
    int wr = wave >> 1, wc = wave & 1;
    int lr = lane & 15, ls = lane >> 4;
    int r0 = blockIdx.x * BM;
    int c0 = blockIdx.y * BN;

    f32x4 acc[4][4];
    #pragma unroll
    for (int m = 0; m < 4; m++)
        #pragma unroll
        for (int n = 0; n < 4; n++) acc[m][n] = (f32x4){0.f,0.f,0.f,0.f};

    for (int k0 = 0; k0 < K; k0 += BK){
        stage_tile(A,  r0, M,  K, k0, As);
        stage_tile(Bt, c0, Nc, K, k0, Bs);
        __syncthreads();
        #pragma unroll
        for (int kk = 0; kk < 2; ++kk){
            bf16x8 af[4], bfg[4];
            #pragma unroll
            for (int m = 0; m < 4; m++){
                int R = wr*64 + m*16 + lr;
                int sl = (kk*4 + ls) ^ (R & 7);
                af[m] = *(const bf16x8*)((const char*)As + R*128 + sl*16);
            }
            #pragma unroll
            for (int n = 0; n < 4; n++){
                int R = wc*64 + n*16 + lr;
                int sl = (kk*4 + ls) ^ (R & 7);
                bfg[n] = *(const bf16x8*)((const char*)Bs + R*128 + sl*16);
            }
            #pragma unroll
            for (int m = 0; m < 4; m++)
                #pragma unroll
                for (int n = 0; n < 4; n++)
                    acc[m][n] = __builtin_amdgcn_mfma_f32_16x16x32_bf16(af[m], bfg[n], acc[m][n], 0, 0, 0);
        }
        __syncthreads();
    }

    // epilogue: C/D layout col=lane&15, row=(lane>>4)*4+reg
    #pragma unroll
    for (int n = 0; n < 4; n++){
        int col = c0 + wc*64 + n*16 + lr;
        float bval = bias ? bias[col] : 0.f;
        #pragma unroll
        for (int m = 0; m < 4; m++){
            #pragma unroll
            for (int j = 0; j < 4; j++){
                int row = r0 + wr*64 + m*16 + ls*4 + j;
                if (row >= M) continue;
                float v = acc[m][n][j] + bval;
                if (relu) v = fmaxf(v, 0.f);
                if (Cf) Cf[(size_t)row*ldc + col] = v;
                if (Cb) Cb[(size_t)row*ldc + col] = __float2bfloat16(v);
            }
        }
    }
}

// ---------------- per-node online-softmax attention (bf16 q/k/v) ----------------
// qkv: [N][384] bf16 (cols 0-127 q, 128-255 k, 256-383 v)
__global__ __launch_bounds__(256) void k_attn(const __hip_bfloat16* __restrict__ qkv,
                                              const int* __restrict__ off,
                                              const int* __restrict__ csr_src,
                                              __hip_bfloat16* __restrict__ a, int N){
    int wid = (blockIdx.x*blockDim.x + threadIdx.x) >> 6;
    int lane = threadIdx.x & 63;
    if (wid >= N) return;
    const ushort* base = (const ushort*)qkv;
    ushort2 qu = ((const ushort2*)(base + (size_t)wid*384))[lane];
    float qx = bf2f(qu.x), qy = bf2f(qu.y);
    int beg = off[wid], end = off[wid+1];
    float m = -INFINITY, dsum = 0.f, ax = 0.f, ay = 0.f;
    for (int e0 = beg; e0 < end; e0 += 64){
        int myidx = (e0 + lane < end) ? csr_src[e0 + lane] : 0;
        int cnt = min(64, end - e0);
        for (int j = 0; j < cnt; ++j){
            int s = __shfl(myidx, j);
            const ushort2* kr = (const ushort2*)(base + (size_t)s*384 + 128);
            ushort2 ku = kr[lane];
            ushort2 vu = kr[lane + 64];
            float p = qx*bf2f(ku.x) + qy*bf2f(ku.y);
            p += __shfl_xor(p, 1);
            p += __shfl_xor(p, 2);
            p += __shfl_xor(p, 4);          // per-head (8-lane) dot over 16 dims
            float es = p * 0.25f;           // 1/sqrt(16)
            float nm = fmaxf(m, es);
            float sc = __expf(m - nm);
            float w  = __expf(es - nm);
            dsum = dsum*sc + w;
            ax = ax*sc + w*bf2f(vu.x);
            ay = ay*sc + w*bf2f(vu.y);
            m = nm;
        }
    }
    float r = (dsum > 0.f) ? 1.f/dsum : 0.f;
    __hip_bfloat162 o2;
    o2.x = __float2bfloat16(ax*r);
    o2.y = __float2bfloat16(ay*r);
    ((__hip_bfloat162*)(a + (size_t)wid*D))[lane] = o2;
}

// ---------------- fused residual + LayerNorm (row per wave), dual-format out ----------------
__global__ __launch_bounds__(256) void k_ln(const float* __restrict__ x1,
                                            const float* __restrict__ x2,
                                            const float* __restrict__ g,
                                            const float* __restrict__ b,
                                            float* __restrict__ yf,
                                            __hip_bfloat16* __restrict__ yb, int N){
    int wid = (blockIdx.x*blockDim.x + threadIdx.x) >> 6;
    int lane = threadIdx.x & 63;
    if (wid >= N) return;
    float2 a_ = *(const float2*)&x1[(size_t)wid*D + lane*2];
    float2 b_ = *(const float2*)&x2[(size_t)wid*D + lane*2];
    float x0 = a_.x + b_.x, x1v = a_.y + b_.y;
    float s = x0 + x1v;
    #pragma unroll
    for (int o = 1; o < 64; o <<= 1) s += __shfl_xor(s, o);
    float mu = s * (1.f/128.f);
    float d0 = x0 - mu, d1 = x1v - mu;
    float vs = d0*d0 + d1*d1;
    #pragma unroll
    for (int o = 1; o < 64; o <<= 1) vs += __shfl_xor(vs, o);
    float inv = rsqrtf(vs*(1.f/128.f) + 1e-5f);
    float2 gg = *(const float2*)&g[lane*2];
    float2 bb = *(const float2*)&b[lane*2];
    float o0 = d0*inv*gg.x + bb.x;
    float o1 = d1*inv*gg.y + bb.y;
    if (yf) *(float2*)&yf[(size_t)wid*D + lane*2] = make_float2(o0, o1);
    if (yb){
        __hip_bfloat162 ob;
        ob.x = __float2bfloat16(o0); ob.y = __float2bfloat16(o1);
        ((__hip_bfloat162*)(yb + (size_t)wid*D))[lane] = ob;
    }
}

extern "C" void kernel_launch(void* const* d_in, const int* in_sizes, int n_in,
                              void* d_out, int out_size, void* d_ws, size_t ws_size,
                              hipStream_t stream){
    const float* h    = (const float*)d_in[0];
    const int*   src  = (const int*)  d_in[1];
    const int*   dst  = (const int*)  d_in[2];
    const float* Wq   = (const float*)d_in[3];
    const float* Wk   = (const float*)d_in[4];
    const float* Wv   = (const float*)d_in[5];
    const float* Wo   = (const float*)d_in[6];
    const float* ln1g = (const float*)d_in[7];
    const float* ln1b = (const float*)d_in[8];
    const float* ln2g = (const float*)d_in[9];
    const float* ln2b = (const float*)d_in[10];
    const float* W1   = (const float*)d_in[11];
    const float* b1   = (const float*)d_in[12];
    const float* W2   = (const float*)d_in[13];
    const float* b2   = (const float*)d_in[14];
    float* out = (float*)d_out;

    const int N = in_sizes[0] / D;
    const int E = in_sizes[1];

    char* ws = (char*)d_ws;
    size_t o = 0;
    const size_t row_bf   = align256((size_t)N * D * sizeof(__hip_bfloat16));   // 12.8 MB
    const size_t row_f    = align256((size_t)N * D * sizeof(float));            // 25.6 MB
    const size_t qkv_bf   = align256((size_t)N * 384 * sizeof(__hip_bfloat16)); // 38.4 MB

    __hip_bfloat16* qkvb = (__hip_bfloat16*)(ws + o); o += qkv_bf;
    __hip_bfloat16* ab   = (__hip_bfloat16*)(ws + o); o += row_bf;
    __hip_bfloat16* t1b  = qkvb;   // [N][512] bf16 overlays qkvb+ab (51.2 MB) after Wo GEMM
    __hip_bfloat16* hb   = (__hip_bfloat16*)(ws + o); o += row_bf;
    __hip_bfloat16* h1b  = hb;     // overlays hb after QKV GEMM
    float* h1f = (float*)(ws + o); o += row_f;
    float* tmp = (float*)(ws + o); o += row_f;
    __hip_bfloat16* Wqkvt = (__hip_bfloat16*)(ws + o); o += align256(384*128*2);
    __hip_bfloat16* Wot   = (__hip_bfloat16*)(ws + o); o += align256(128*128*2);
    __hip_bfloat16* W1t   = (__hip_bfloat16*)(ws + o); o += align256(512*128*2);
    __hip_bfloat16* W2t   = (__hip_bfloat16*)(ws + o); o += align256(128*512*2);
    int* cnt  = (int*)(ws + o); o += align256((size_t)N*4);
    int* cur  = (int*)(ws + o); o += align256((size_t)N*4);
    int* offp = (int*)(ws + o); o += align256((size_t)(N+1)*4);
    int* csr  = (int*)(ws + o); o += align256((size_t)E*4);

    // --- prep: casts/transposes + CSR build ---
    (void)hipMemsetAsync(cnt, 0, (size_t)N*4, stream);
    int eb = min((E + 255)/256, 4096);
    k_count<<<eb, 256, 0, stream>>>(dst, E, cnt);

    k_cast<<<(N*D/4 + 255)/256, 256, 0, stream>>>(h, hb, N*D/4);
    k_prep_w<<<(128*128 + 255)/256, 256, 0, stream>>>(Wq, Wqkvt,           128, 128);
    k_prep_w<<<(128*128 + 255)/256, 256, 0, stream>>>(Wk, Wqkvt + 128*128, 128, 128);
    k_prep_w<<<(128*128 + 255)/256, 256, 0, stream>>>(Wv, Wqkvt + 256*128, 128, 128);
    k_prep_w<<<(128*128 + 255)/256, 256, 0, stream>>>(Wo, Wot, 128, 128);
    k_prep_w<<<(512*128 + 255)/256, 256, 0, stream>>>(W1, W1t, 128, 512);
    k_prep_w<<<(512*128 + 255)/256, 256, 0, stream>>>(W2, W2t, 512, 128);

    k_scan   <<<1, 1024, 0, stream>>>(cnt, N, offp, cur);
    k_scatter<<<eb, 256, 0, stream>>>(src, dst, E, cur, csr);

    int mb = (N + BM - 1)/BM;   // 391

    // --- fused QKV projection (virtual Nc=384) ---
    k_mfma_gemm<<<dim3(mb,3), 256, 0, stream>>>(hb, Wqkvt, N, 384, 128, 384,
                                                nullptr, 0, nullptr, qkvb);

    // --- sparse attention ---
    k_attn<<<(N*64 + 255)/256, 256, 0, stream>>>(qkvb, offp, csr, ab, N);

    // --- output projection + LN1 ---
    k_mfma_gemm<<<dim3(mb,1), 256, 0, stream>>>(ab, Wot, N, 128, 128, 128,
                                                nullptr, 0, tmp, nullptr);
    int lb = (N*64 + 255)/256;
    k_ln<<<lb, 256, 0, stream>>>(h, tmp, ln1g, ln1b, h1f, h1b, N);

    // --- FFN ---
    k_mfma_gemm<<<dim3(mb,4), 256, 0, stream>>>(h1b, W1t, N, 512, 128, 512,
                                                b1, 1, nullptr, t1b);
    k_mfma_gemm<<<dim3(mb,1), 256, 0, stream>>>(t1b, W2t, N, 128, 512, 128,
                                                b2, 0, tmp, nullptr);

    // --- LN2 -> out ---
    k_ln<<<lb, 256, 0, stream>>>(h1f, tmp, ln2g, ln2b, out, nullptr, N);
}

// Round 4
// 453.753 us; speedup vs baseline: 2.1018x; 1.3165x over previous
//
#include <hip/hip_runtime.h>
#include <hip/hip_bf16.h>
#include <math.h>

#define D   128
#define FFD 512

typedef __attribute__((ext_vector_type(8))) short bf16x8;
typedef __attribute__((ext_vector_type(4))) float f32x4;

static inline size_t align256(size_t x){ return (x + 255) & ~(size_t)255; }

__device__ __forceinline__ float bf2f(unsigned short u){
    union { unsigned int i; float f; } x; x.i = ((unsigned int)u) << 16; return x.f;
}
__device__ __forceinline__ unsigned short f2bf(float f){
    return __builtin_bit_cast(unsigned short, __float2bfloat16(f));
}

// ---------------- CSR build ----------------
__global__ __launch_bounds__(256) void k_count(const int* __restrict__ dst, int E,
                                               int* __restrict__ cnt){
    int i = blockIdx.x*blockDim.x + threadIdx.x;
    int stride = gridDim.x*blockDim.x;
    for (; i < E; i += stride) atomicAdd(&cnt[dst[i]], 1);
}

// hierarchical scan: block sums -> scan sums -> per-block offsets
__global__ __launch_bounds__(256) void k_bsum(const int* __restrict__ cnt, int N,
                                              int* __restrict__ bsum){
    int id = blockIdx.x*256 + threadIdx.x;
    int v = (id < N) ? cnt[id] : 0;
    #pragma unroll
    for (int o = 1; o < 64; o <<= 1) v += __shfl_xor(v, o);
    __shared__ int w4[4];
    if ((threadIdx.x & 63) == 0) w4[threadIdx.x >> 6] = v;
    __syncthreads();
    if (threadIdx.x == 0) bsum[blockIdx.x] = w4[0] + w4[1] + w4[2] + w4[3];
}

__global__ __launch_bounds__(1024) void k_scanb(const int* __restrict__ bsum, int NB,
                                                int* __restrict__ ebase,
                                                int* __restrict__ off, int N){
    __shared__ int sh[1024];
    int tid = threadIdx.x;
    int v = (tid < NB) ? bsum[tid] : 0;
    sh[tid] = v; __syncthreads();
    for (int o = 1; o < 1024; o <<= 1){
        int t = (tid >= o) ? sh[tid-o] : 0;
        __syncthreads();
        sh[tid] += t;
        __syncthreads();
    }
    if (tid < NB) ebase[tid] = sh[tid] - v;
    if (tid == NB-1) off[N] = sh[tid];
}

__global__ __launch_bounds__(256) void k_off(const int* __restrict__ cnt, int N,
                                             const int* __restrict__ ebase,
                                             int* __restrict__ off, int* __restrict__ cur){
    __shared__ int sh[256];
    int tid = threadIdx.x;
    int id = blockIdx.x*256 + tid;
    int v = (id < N) ? cnt[id] : 0;
    sh[tid] = v; __syncthreads();
    for (int o = 1; o < 256; o <<= 1){
        int t = (tid >= o) ? sh[tid-o] : 0;
        __syncthreads();
        sh[tid] += t;
        __syncthreads();
    }
    int excl = sh[tid] - v;
    int base = ebase[blockIdx.x];
    if (id < N){ off[id] = base + excl; cur[id] = base + excl; }
}

__global__ __launch_bounds__(256) void k_scatter(const int* __restrict__ src,
                                                 const int* __restrict__ dst, int E,
                                                 int* __restrict__ cur,
                                                 int* __restrict__ csr_src){
    int i = blockIdx.x*blockDim.x + threadIdx.x;
    int stride = gridDim.x*blockDim.x;
    for (; i < E; i += stride){
        int p = atomicAdd(&cur[dst[i]], 1);
        csr_src[p] = src[i];
    }
}

// ---------------- prep ----------------
__global__ __launch_bounds__(256) void k_cast(const float* __restrict__ x,
                                              __hip_bfloat16* __restrict__ y, int n4){
    int i = blockIdx.x*blockDim.x + threadIdx.x;
    if (i >= n4) return;
    float4 f = ((const float4*)x)[i];
    ushort4 u;
    u.x = f2bf(f.x); u.y = f2bf(f.y);
    u.z = f2bf(f.z); u.w = f2bf(f.w);
    ((ushort4*)y)[i] = u;
}

__global__ __launch_bounds__(256) void k_prep_w(const float* __restrict__ W,
                                                __hip_bfloat16* __restrict__ Wt,
                                                int K, int Nc){
    int id = blockIdx.x*blockDim.x + threadIdx.x;
    if (id >= K*Nc) return;
    int n = id / K, kk = id % K;
    Wt[id] = __float2bfloat16(W[(size_t)kk*Nc + n]);
}

// ---------------- MFMA bf16 GEMM, templated epilogue ----------------
// MODE 0: plain bias/relu -> bf16 C [M][Nc]
// MODE 1: QKV scatter: region(c0/128) 0->qb[N][128], 1/2 -> kvb interleaved [N][256]
// MODE 2: bias + residual + LayerNorm -> yf f32 (+ yb bf16)
#define BM 128
#define BN 128
#define BK 64

__device__ __forceinline__ void stage_tile(const __hip_bfloat16* __restrict__ src,
                                           int row_base, int row_limit, int K, int k0,
                                           __hip_bfloat16* lds){
    int tid = threadIdx.x;
    int wave = tid >> 6;
    #pragma unroll
    for (int i = 0; i < 4; ++i){
        int c = i*256 + tid;          // 16B chunk: 1024 chunks = 128 rows x 8 slots
        int r = c >> 3, s = c & 7;
        int sg = s ^ (r & 7);         // inverse swizzle on source
        int gr = row_base + r; if (gr >= row_limit) gr = row_limit - 1;
        const __hip_bfloat16* gp = src + (size_t)gr*K + k0 + sg*8;
        char* lp = (char*)lds + (i*256 + wave*64)*16;   // wave-uniform base
        __builtin_amdgcn_global_load_lds((const __attribute__((address_space(1))) void*)gp,
                                         (__attribute__((address_space(3))) void*)lp,
                                         16, 0, 0);
    }
}

template<int MODE>
__global__ __launch_bounds__(256) void k_gemm(
    const __hip_bfloat16* __restrict__ A,   // [M][K]
    const __hip_bfloat16* __restrict__ Bt,  // [Nc][K]
    int M, int Nc, int K,
    const float* __restrict__ bias, int relu,
    __hip_bfloat16* __restrict__ Cb,                       // MODE 0
    __hip_bfloat16* __restrict__ qb, __hip_bfloat16* __restrict__ kvb,  // MODE 1
    const float* __restrict__ resid, const float* __restrict__ lg,
    const float* __restrict__ lb,
    float* __restrict__ yf, __hip_bfloat16* __restrict__ yb){           // MODE 2
    __shared__ __hip_bfloat16 As[BM*BK];
    __shared__ __hip_bfloat16 Bs[BN*BK];
    __shared__ float red[2][BM][2];
    int tid = threadIdx.x;
    int lane = tid & 63, wave = tid >> 6;
    int wr = wave >> 1, wc = wave & 1;
    int lr = lane & 15, ls = lane >> 4;
    int r0 = blockIdx.x * BM;
    int c0 = blockIdx.y * BN;

    f32x4 acc[4][4];
    #pragma unroll
    for (int m = 0; m < 4; m++)
        #pragma unroll
        for (int n = 0; n < 4; n++) acc[m][n] = (f32x4){0.f,0.f,0.f,0.f};

    for (int k0 = 0; k0 < K; k0 += BK){
        stage_tile(A,  r0, M,  K, k0, As);
        stage_tile(Bt, c0, Nc, K, k0, Bs);
        __syncthreads();
        #pragma unroll
        for (int kk = 0; kk < 2; ++kk){
            bf16x8 af[4], bfg[4];
            #pragma unroll
            for (int m = 0; m < 4; m++){
                int R = wr*64 + m*16 + lr;
                int sl = (kk*4 + ls) ^ (R & 7);
                af[m] = *(const bf16x8*)((const char*)As + R*128 + sl*16);
            }
            #pragma unroll
            for (int n = 0; n < 4; n++){
                int R = wc*64 + n*16 + lr;
                int sl = (kk*4 + ls) ^ (R & 7);
                bfg[n] = *(const bf16x8*)((const char*)Bs + R*128 + sl*16);
            }
            #pragma unroll
            for (int m = 0; m < 4; m++)
                #pragma unroll
                for (int n = 0; n < 4; n++)
                    acc[m][n] = __builtin_amdgcn_mfma_f32_16x16x32_bf16(af[m], bfg[n], acc[m][n], 0, 0, 0);
        }
        __syncthreads();
    }

    // C/D layout: col=lane&15, row=(lane>>4)*4+reg
    if (MODE == 0){
        #pragma unroll
        for (int n = 0; n < 4; n++){
            int col = c0 + wc*64 + n*16 + lr;
            float bval = bias ? bias[col] : 0.f;
            #pragma unroll
            for (int m = 0; m < 4; m++){
                #pragma unroll
                for (int j = 0; j < 4; j++){
                    int row = r0 + wr*64 + m*16 + ls*4 + j;
                    if (row >= M) continue;
                    float v = acc[m][n][j] + bval;
                    if (relu) v = fmaxf(v, 0.f);
                    Cb[(size_t)row*Nc + col] = __float2bfloat16(v);
                }
            }
        }
    } else if (MODE == 1){
        int region = c0 >> 7;    // 0=q, 1=k, 2=v
        #pragma unroll
        for (int n = 0; n < 4; n++){
            int c16 = wc*64 + n*16 + lr;   // 0..127 within region
            #pragma unroll
            for (int m = 0; m < 4; m++){
                #pragma unroll
                for (int j = 0; j < 4; j++){
                    int row = r0 + wr*64 + m*16 + ls*4 + j;
                    if (row >= M) continue;
                    unsigned short v = f2bf(acc[m][n][j]);
                    if (region == 0)
                        ((unsigned short*)qb)[(size_t)row*128 + c16] = v;
                    else if (region == 1)
                        ((unsigned short*)kvb)[(size_t)row*256 + (c16>>1)*4 + (c16&1)] = v;
                    else
                        ((unsigned short*)kvb)[(size_t)row*256 + (c16>>1)*4 + 2 + (c16&1)] = v;
                }
            }
        }
    } else {
        // residual + bias, stats
        #pragma unroll
        for (int m = 0; m < 4; m++){
            #pragma unroll
            for (int j = 0; j < 4; j++){
                int row = r0 + wr*64 + m*16 + ls*4 + j;
                float s = 0.f, q = 0.f;
                if (row < M){
                    #pragma unroll
                    for (int n = 0; n < 4; n++){
                        int col = wc*64 + n*16 + lr;
                        float bval = bias ? bias[col] : 0.f;
                        float v = acc[m][n][j] + bval + resid[(size_t)row*128 + col];
                        acc[m][n][j] = v;
                        s += v; q += v*v;
                    }
                }
                #pragma unroll
                for (int o = 1; o < 16; o <<= 1){
                    s += __shfl_xor(s, o);
                    q += __shfl_xor(q, o);
                }
                if (lr == 0 && row < M){
                    int rloc = wr*64 + m*16 + ls*4 + j;
                    red[0][rloc][wc] = s;
                    red[1][rloc][wc] = q;
                }
            }
        }
        __syncthreads();
        #pragma unroll
        for (int m = 0; m < 4; m++){
            #pragma unroll
            for (int j = 0; j < 4; j++){
                int rloc = wr*64 + m*16 + ls*4 + j;
                int row = r0 + rloc;
                if (row >= M) continue;
                float mu  = (red[0][rloc][0] + red[0][rloc][1]) * (1.f/128.f);
                float eq  = (red[1][rloc][0] + red[1][rloc][1]) * (1.f/128.f);
                float var = fmaxf(eq - mu*mu, 0.f);
                float inv = rsqrtf(var + 1e-5f);
                #pragma unroll
                for (int n = 0; n < 4; n++){
                    int col = wc*64 + n*16 + lr;
                    float o = (acc[m][n][j] - mu)*inv*lg[col] + lb[col];
                    if (yf) yf[(size_t)row*128 + col] = o;
                    if (yb) yb[(size_t)row*128 + col] = __float2bfloat16(o);
                }
            }
        }
    }
}

// ---------------- per-node online-softmax attention ----------------
// qb: [N][128] bf16 ; kvb: [N][256] bf16 interleaved {k2l,k2l+1,v2l,v2l+1} per lane l
__global__ __launch_bounds__(256) void k_attn(const __hip_bfloat16* __restrict__ qb,
                                              const __hip_bfloat16* __restrict__ kvb,
                                              const int* __restrict__ off,
                                              const int* __restrict__ csr_src,
                                              __hip_bfloat16* __restrict__ a, int N){
    int wid = (blockIdx.x*blockDim.x + threadIdx.x) >> 6;
    int lane = threadIdx.x & 63;
    if (wid >= N) return;
    ushort2 qu = ((const ushort2*)qb)[(size_t)wid*64 + lane];
    float qx = bf2f(qu.x), qy = bf2f(qu.y);
    const ushort4* kv = (const ushort4*)kvb;
    int beg = off[wid], end = off[wid+1];
    float m = -INFINITY, dsum = 0.f, ax = 0.f, ay = 0.f;
    for (int e0 = beg; e0 < end; e0 += 64){
        int myidx = (e0 + lane < end) ? csr_src[e0 + lane] : 0;
        int cnt = min(64, end - e0);
        int j = 0;
        for (; j + 3 < cnt; j += 4){
            int s0 = __shfl(myidx, j);
            int s1 = __shfl(myidx, j+1);
            int s2 = __shfl(myidx, j+2);
            int s3 = __shfl(myidx, j+3);
            ushort4 u0 = kv[(size_t)s0*64 + lane];
            ushort4 u1 = kv[(size_t)s1*64 + lane];
            ushort4 u2 = kv[(size_t)s2*64 + lane];
            ushort4 u3 = kv[(size_t)s3*64 + lane];
            float p0 = qx*bf2f(u0.x) + qy*bf2f(u0.y);
            float p1 = qx*bf2f(u1.x) + qy*bf2f(u1.y);
            float p2 = qx*bf2f(u2.x) + qy*bf2f(u2.y);
            float p3 = qx*bf2f(u3.x) + qy*bf2f(u3.y);
            #pragma unroll
            for (int o = 1; o < 8; o <<= 1){
                p0 += __shfl_xor(p0, o);
                p1 += __shfl_xor(p1, o);
                p2 += __shfl_xor(p2, o);
                p3 += __shfl_xor(p3, o);
            }
            float es0 = p0*0.25f, es1 = p1*0.25f, es2 = p2*0.25f, es3 = p3*0.25f;
            float nm = fmaxf(fmaxf(m, fmaxf(es0, es1)), fmaxf(es2, es3));
            float sc = __expf(m - nm);
            float w0 = __expf(es0 - nm), w1 = __expf(es1 - nm);
            float w2 = __expf(es2 - nm), w3 = __expf(es3 - nm);
            dsum = dsum*sc + ((w0+w1) + (w2+w3));
            ax = ax*sc + w0*bf2f(u0.z) + w1*bf2f(u1.z) + w2*bf2f(u2.z) + w3*bf2f(u3.z);
            ay = ay*sc + w0*bf2f(u0.w) + w1*bf2f(u1.w) + w2*bf2f(u2.w) + w3*bf2f(u3.w);
            m = nm;
        }
        for (; j < cnt; ++j){
            int s = __shfl(myidx, j);
            ushort4 u = kv[(size_t)s*64 + lane];
            float p = qx*bf2f(u.x) + qy*bf2f(u.y);
            #pragma unroll
            for (int o = 1; o < 8; o <<= 1) p += __shfl_xor(p, o);
            float es = p*0.25f;
            float nm = fmaxf(m, es);
            float sc = __expf(m - nm);
            float w  = __expf(es - nm);
            dsum = dsum*sc + w;
            ax = ax*sc + w*bf2f(u.z);
            ay = ay*sc + w*bf2f(u.w);
            m = nm;
        }
    }
    float r = (dsum > 0.f) ? 1.f/dsum : 0.f;
    __hip_bfloat162 o2;
    o2.x = __float2bfloat16(ax*r);
    o2.y = __float2bfloat16(ay*r);
    ((__hip_bfloat162*)(a + (size_t)wid*D))[lane] = o2;
}

extern "C" void kernel_launch(void* const* d_in, const int* in_sizes, int n_in,
                              void* d_out, int out_size, void* d_ws, size_t ws_size,
                              hipStream_t stream){
    const float* h    = (const float*)d_in[0];
    const int*   src  = (const int*)  d_in[1];
    const int*   dst  = (const int*)  d_in[2];
    const float* Wq   = (const float*)d_in[3];
    const float* Wk   = (const float*)d_in[4];
    const float* Wv   = (const float*)d_in[5];
    const float* Wo   = (const float*)d_in[6];
    const float* ln1g = (const float*)d_in[7];
    const float* ln1b = (const float*)d_in[8];
    const float* ln2g = (const float*)d_in[9];
    const float* ln2b = (const float*)d_in[10];
    const float* W1   = (const float*)d_in[11];
    const float* b1   = (const float*)d_in[12];
    const float* W2   = (const float*)d_in[13];
    const float* b2   = (const float*)d_in[14];
    float* out = (float*)d_out;

    const int N = in_sizes[0] / D;
    const int E = in_sizes[1];

    char* ws = (char*)d_ws;
    size_t o = 0;
    const size_t row_bf = align256((size_t)N * D * sizeof(__hip_bfloat16));    // 12.8 MB
    const size_t kv_bf  = align256((size_t)N * 256 * sizeof(__hip_bfloat16));  // 25.6 MB
    const size_t row_f  = align256((size_t)N * D * sizeof(float));             // 25.6 MB

    __hip_bfloat16* qb  = (__hip_bfloat16*)(ws + o); o += row_bf;
    __hip_bfloat16* kvb = (__hip_bfloat16*)(ws + o); o += kv_bf;
    __hip_bfloat16* ab  = (__hip_bfloat16*)(ws + o); o += row_bf;
    __hip_bfloat16* t1b = qb;   // [N][512] bf16 overlays qb+kvb+ab (51.2MB) after Wo+LN1
    __hip_bfloat16* hb  = (__hip_bfloat16*)(ws + o); o += row_bf;
    __hip_bfloat16* h1b = hb;   // overlays hb after QKV GEMM
    float* h1f = (float*)(ws + o); o += row_f;
    __hip_bfloat16* Wqkvt = (__hip_bfloat16*)(ws + o); o += align256(384*128*2);
    __hip_bfloat16* W1t   = (__hip_bfloat16*)(ws + o); o += align256(512*128*2);
    __hip_bfloat16* W2t   = (__hip_bfloat16*)(ws + o); o += align256(128*512*2);
    __hip_bfloat16* Wot   = (__hip_bfloat16*)(ws + o); o += align256(128*128*2);
    int* cnt   = (int*)(ws + o); o += align256((size_t)N*4);
    int* cur   = (int*)(ws + o); o += align256((size_t)N*4);
    int* offp  = (int*)(ws + o); o += align256((size_t)(N+1)*4);
    int* bsum  = (int*)(ws + o); o += align256(1024*4);
    int* ebase = (int*)(ws + o); o += align256(1024*4);
    int* csr   = (int*)(ws + o); o += align256((size_t)E*4);

    const int NB = (N + 255)/256;   // 196

    // --- prep + CSR build ---
    (void)hipMemsetAsync(cnt, 0, (size_t)N*4, stream);
    int eb = min((E + 255)/256, 4096);
    k_count<<<eb, 256, 0, stream>>>(dst, E, cnt);

    k_cast<<<(N*D/4 + 255)/256, 256, 0, stream>>>(h, hb, N*D/4);
    k_prep_w<<<(128*128 + 255)/256, 256, 0, stream>>>(Wq, Wqkvt,           128, 128);
    k_prep_w<<<(128*128 + 255)/256, 256, 0, stream>>>(Wk, Wqkvt + 128*128, 128, 128);
    k_prep_w<<<(128*128 + 255)/256, 256, 0, stream>>>(Wv, Wqkvt + 256*128, 128, 128);
    k_prep_w<<<(128*128 + 255)/256, 256, 0, stream>>>(Wo, Wot, 128, 128);
    k_prep_w<<<(512*128 + 255)/256, 256, 0, stream>>>(W1, W1t, 128, 512);
    k_prep_w<<<(512*128 + 255)/256, 256, 0, stream>>>(W2, W2t, 512, 128);

    k_bsum <<<NB, 256, 0, stream>>>(cnt, N, bsum);
    k_scanb<<<1, 1024, 0, stream>>>(bsum, NB, ebase, offp, N);
    k_off  <<<NB, 256, 0, stream>>>(cnt, N, ebase, offp, cur);
    k_scatter<<<eb, 256, 0, stream>>>(src, dst, E, cur, csr);

    int mb = (N + BM - 1)/BM;   // 391

    // --- QKV projection (scatter epilogue: q + interleaved kv) ---
    k_gemm<1><<<dim3(mb,3), 256, 0, stream>>>(hb, Wqkvt, N, 384, 128,
        nullptr, 0, nullptr, qb, kvb, nullptr, nullptr, nullptr, nullptr, nullptr);

    // --- sparse attention ---
    k_attn<<<(N*64 + 255)/256, 256, 0, stream>>>(qb, kvb, offp, csr, ab, N);

    // --- Wo projection + residual(h) + LN1 -> h1f, h1b ---
    k_gemm<2><<<dim3(mb,1), 256, 0, stream>>>(ab, Wot, N, 128, 128,
        nullptr, 0, nullptr, nullptr, nullptr, h, ln1g, ln1b, h1f, h1b);

    // --- FFN1: relu(h1b @ W1 + b1) -> t1b ---
    k_gemm<0><<<dim3(mb,4), 256, 0, stream>>>(h1b, W1t, N, 512, 128,
        b1, 1, t1b, nullptr, nullptr, nullptr, nullptr, nullptr, nullptr, nullptr);

    // --- FFN2 + residual(h1f) + LN2 -> out ---
    k_gemm<2><<<dim3(mb,1), 256, 0, stream>>>(t1b, W2t, N, 128, 512,
        b2, 0, nullptr, nullptr, nullptr, h1f, ln2g, ln2b, out, nullptr);
}

// Round 5
// 417.827 us; speedup vs baseline: 2.2826x; 1.0860x over previous
//
#include <hip/hip_runtime.h>
#include <hip/hip_bf16.h>
#include <math.h>

#define D   128
#define FFD 512
#define NPART 8

typedef __attribute__((ext_vector_type(8))) short bf16x8;
typedef __attribute__((ext_vector_type(4))) float f32x4;

static inline size_t align256(size_t x){ return (x + 255) & ~(size_t)255; }

__device__ __forceinline__ float bf2f(unsigned short u){
    union { unsigned int i; float f; } x; x.i = ((unsigned int)u) << 16; return x.f;
}
__device__ __forceinline__ unsigned short f2bf(float f){
    return __builtin_bit_cast(unsigned short, __float2bfloat16(f));
}

// ---------------- CSR build (XCD-range-partitioned count & scatter) ----------------
// part = blockIdx.x & 7 ~ XCD id (round-robin dispatch). Each part handles only
// dst in [part*N/8,(part+1)*N/8): atomics + csr writes stay in that XCD's L2,
// so lines fill before eviction (fixes 102MB partial-line write traffic).
__global__ __launch_bounds__(256) void k_count(const int* __restrict__ dst, int E,
                                               int* __restrict__ cnt, int N){
    int part = blockIdx.x & (NPART-1);
    int lo = (int)((long long)part     * N / NPART);
    int hi = (int)((long long)(part+1) * N / NPART);
    int stride = (gridDim.x >> 3) * 256;
    for (int i = (blockIdx.x >> 3)*256 + threadIdx.x; i < E; i += stride){
        int d = dst[i];
        if (d >= lo && d < hi) atomicAdd(&cnt[d], 1);
    }
}

// hierarchical scan: block sums -> scan sums -> per-block offsets
__global__ __launch_bounds__(256) void k_bsum(const int* __restrict__ cnt, int N,
                                              int* __restrict__ bsum){
    int id = blockIdx.x*256 + threadIdx.x;
    int v = (id < N) ? cnt[id] : 0;
    #pragma unroll
    for (int o = 1; o < 64; o <<= 1) v += __shfl_xor(v, o);
    __shared__ int w4[4];
    if ((threadIdx.x & 63) == 0) w4[threadIdx.x >> 6] = v;
    __syncthreads();
    if (threadIdx.x == 0) bsum[blockIdx.x] = w4[0] + w4[1] + w4[2] + w4[3];
}

__global__ __launch_bounds__(1024) void k_scanb(const int* __restrict__ bsum, int NB,
                                                int* __restrict__ ebase,
                                                int* __restrict__ off, int N){
    __shared__ int sh[1024];
    int tid = threadIdx.x;
    int v = (tid < NB) ? bsum[tid] : 0;
    sh[tid] = v; __syncthreads();
    for (int o = 1; o < 1024; o <<= 1){
        int t = (tid >= o) ? sh[tid-o] : 0;
        __syncthreads();
        sh[tid] += t;
        __syncthreads();
    }
    if (tid < NB) ebase[tid] = sh[tid] - v;
    if (tid == NB-1) off[N] = sh[tid];
}

__global__ __launch_bounds__(256) void k_off(const int* __restrict__ cnt, int N,
                                             const int* __restrict__ ebase,
                                             int* __restrict__ off, int* __restrict__ cur){
    __shared__ int sh[256];
    int tid = threadIdx.x;
    int id = blockIdx.x*256 + tid;
    int v = (id < N) ? cnt[id] : 0;
    sh[tid] = v; __syncthreads();
    for (int o = 1; o < 256; o <<= 1){
        int t = (tid >= o) ? sh[tid-o] : 0;
        __syncthreads();
        sh[tid] += t;
        __syncthreads();
    }
    int excl = sh[tid] - v;
    int base = ebase[blockIdx.x];
    if (id < N){ off[id] = base + excl; cur[id] = base + excl; }
}

__global__ __launch_bounds__(256) void k_scatter(const int* __restrict__ src,
                                                 const int* __restrict__ dst, int E,
                                                 int* __restrict__ cur,
                                                 int* __restrict__ csr_src, int N){
    int part = blockIdx.x & (NPART-1);
    int lo = (int)((long long)part     * N / NPART);
    int hi = (int)((long long)(part+1) * N / NPART);
    int stride = (gridDim.x >> 3) * 256;
    for (int i = (blockIdx.x >> 3)*256 + threadIdx.x; i < E; i += stride){
        int d = dst[i];
        if (d >= lo && d < hi){
            int p = atomicAdd(&cur[d], 1);
            csr_src[p] = src[i];
        }
    }
}

// ---------------- prep ----------------
__global__ __launch_bounds__(256) void k_cast(const float* __restrict__ x,
                                              __hip_bfloat16* __restrict__ y, int n4){
    int i = blockIdx.x*blockDim.x + threadIdx.x;
    if (i >= n4) return;
    float4 f = ((const float4*)x)[i];
    ushort4 u;
    u.x = f2bf(f.x); u.y = f2bf(f.y);
    u.z = f2bf(f.z); u.w = f2bf(f.w);
    ((ushort4*)y)[i] = u;
}

__global__ __launch_bounds__(256) void k_prep_w(const float* __restrict__ W,
                                                __hip_bfloat16* __restrict__ Wt,
                                                int K, int Nc){
    int id = blockIdx.x*blockDim.x + threadIdx.x;
    if (id >= K*Nc) return;
    int n = id / K, kk = id % K;
    Wt[id] = __float2bfloat16(W[(size_t)kk*Nc + n]);
}

// ---------------- MFMA bf16 GEMM, templated epilogue ----------------
// MODE 0: plain bias/relu -> bf16 C [M][Nc]
// MODE 1: QKV scatter: region(c0/128) 0->qb[N][128], 1/2 -> kvb interleaved [N][256]
// MODE 2: bias + residual + LayerNorm -> yf f32 (+ yb bf16)
#define BM 128
#define BN 128
#define BK 64

__device__ __forceinline__ void stage_tile(const __hip_bfloat16* __restrict__ src,
                                           int row_base, int row_limit, int K, int k0,
                                           __hip_bfloat16* lds){
    int tid = threadIdx.x;
    int wave = tid >> 6;
    #pragma unroll
    for (int i = 0; i < 4; ++i){
        int c = i*256 + tid;          // 16B chunk: 1024 chunks = 128 rows x 8 slots
        int r = c >> 3, s = c & 7;
        int sg = s ^ (r & 7);         // inverse swizzle on source
        int gr = row_base + r; if (gr >= row_limit) gr = row_limit - 1;
        const __hip_bfloat16* gp = src + (size_t)gr*K + k0 + sg*8;
        char* lp = (char*)lds + (i*256 + wave*64)*16;   // wave-uniform base
        __builtin_amdgcn_global_load_lds((const __attribute__((address_space(1))) void*)gp,
                                         (__attribute__((address_space(3))) void*)lp,
                                         16, 0, 0);
    }
}

template<int MODE>
__global__ __launch_bounds__(256) void k_gemm(
    const __hip_bfloat16* __restrict__ A,   // [M][K]
    const __hip_bfloat16* __restrict__ Bt,  // [Nc][K]
    int M, int Nc, int K,
    const float* __restrict__ bias, int relu,
    __hip_bfloat16* __restrict__ Cb,                       // MODE 0
    __hip_bfloat16* __restrict__ qb, __hip_bfloat16* __restrict__ kvb,  // MODE 1
    const float* __restrict__ resid, const float* __restrict__ lg,
    const float* __restrict__ lb,
    float* __restrict__ yf, __hip_bfloat16* __restrict__ yb){           // MODE 2
    __shared__ __hip_bfloat16 As[BM*BK];
    __shared__ __hip_bfloat16 Bs[BN*BK];
    __shared__ float red[2][BM][2];
    int tid = threadIdx.x;
    int lane = tid & 63, wave = tid >> 6;
    int wr = wave >> 1, wc = wave & 1;
    int lr = lane & 15, ls = lane >> 4;
    int r0 = blockIdx.x * BM;
    int c0 = blockIdx.y * BN;

    f32x4 acc[4][4];
    #pragma unroll
    for (int m = 0; m < 4; m++)
        #pragma unroll
        for (int n = 0; n < 4; n++) acc[m][n] = (f32x4){0.f,0.f,0.f,0.f};

    for (int k0 = 0; k0 < K; k0 += BK){
        stage_tile(A,  r0, M,  K, k0, As);
        stage_tile(Bt, c0, Nc, K, k0, Bs);
        __syncthreads();
        #pragma unroll
        for (int kk = 0; kk < 2; ++kk){
            bf16x8 af[4], bfg[4];
            #pragma unroll
            for (int m = 0; m < 4; m++){
                int R = wr*64 + m*16 + lr;
                int sl = (kk*4 + ls) ^ (R & 7);
                af[m] = *(const bf16x8*)((const char*)As + R*128 + sl*16);
            }
            #pragma unroll
            for (int n = 0; n < 4; n++){
                int R = wc*64 + n*16 + lr;
                int sl = (kk*4 + ls) ^ (R & 7);
                bfg[n] = *(const bf16x8*)((const char*)Bs + R*128 + sl*16);
            }
            #pragma unroll
            for (int m = 0; m < 4; m++)
                #pragma unroll
                for (int n = 0; n < 4; n++)
                    acc[m][n] = __builtin_amdgcn_mfma_f32_16x16x32_bf16(af[m], bfg[n], acc[m][n], 0, 0, 0);
        }
        __syncthreads();
    }

    // C/D layout: col=lane&15, row=(lane>>4)*4+reg
    if (MODE == 0){
        #pragma unroll
        for (int n = 0; n < 4; n++){
            int col = c0 + wc*64 + n*16 + lr;
            float bval = bias ? bias[col] : 0.f;
            #pragma unroll
            for (int m = 0; m < 4; m++){
                #pragma unroll
                for (int j = 0; j < 4; j++){
                    int row = r0 + wr*64 + m*16 + ls*4 + j;
                    if (row >= M) continue;
                    float v = acc[m][n][j] + bval;
                    if (relu) v = fmaxf(v, 0.f);
                    Cb[(size_t)row*Nc + col] = __float2bfloat16(v);
                }
            }
        }
    } else if (MODE == 1){
        int region = c0 >> 7;    // 0=q, 1=k, 2=v
        #pragma unroll
        for (int n = 0; n < 4; n++){
            int c16 = wc*64 + n*16 + lr;   // 0..127 within region
            #pragma unroll
            for (int m = 0; m < 4; m++){
                #pragma unroll
                for (int j = 0; j < 4; j++){
                    int row = r0 + wr*64 + m*16 + ls*4 + j;
                    if (row >= M) continue;
                    unsigned short v = f2bf(acc[m][n][j]);
                    if (region == 0)
                        ((unsigned short*)qb)[(size_t)row*128 + c16] = v;
                    else if (region == 1)
                        ((unsigned short*)kvb)[(size_t)row*256 + (c16>>1)*4 + (c16&1)] = v;
                    else
                        ((unsigned short*)kvb)[(size_t)row*256 + (c16>>1)*4 + 2 + (c16&1)] = v;
                }
            }
        }
    } else {
        // residual + bias, stats
        #pragma unroll
        for (int m = 0; m < 4; m++){
            #pragma unroll
            for (int j = 0; j < 4; j++){
                int row = r0 + wr*64 + m*16 + ls*4 + j;
                float s = 0.f, q = 0.f;
                if (row < M){
                    #pragma unroll
                    for (int n = 0; n < 4; n++){
                        int col = wc*64 + n*16 + lr;
                        float bval = bias ? bias[col] : 0.f;
                        float v = acc[m][n][j] + bval + resid[(size_t)row*128 + col];
                        acc[m][n][j] = v;
                        s += v; q += v*v;
                    }
                }
                #pragma unroll
                for (int o = 1; o < 16; o <<= 1){
                    s += __shfl_xor(s, o);
                    q += __shfl_xor(q, o);
                }
                if (lr == 0 && row < M){
                    int rloc = wr*64 + m*16 + ls*4 + j;
                    red[0][rloc][wc] = s;
                    red[1][rloc][wc] = q;
                }
            }
        }
        __syncthreads();
        #pragma unroll
        for (int m = 0; m < 4; m++){
            #pragma unroll
            for (int j = 0; j < 4; j++){
                int rloc = wr*64 + m*16 + ls*4 + j;
                int row = r0 + rloc;
                if (row >= M) continue;
                float mu  = (red[0][rloc][0] + red[0][rloc][1]) * (1.f/128.f);
                float eq  = (red[1][rloc][0] + red[1][rloc][1]) * (1.f/128.f);
                float var = fmaxf(eq - mu*mu, 0.f);
                float inv = rsqrtf(var + 1e-5f);
                #pragma unroll
                for (int n = 0; n < 4; n++){
                    int col = wc*64 + n*16 + lr;
                    float o = (acc[m][n][j] - mu)*inv*lg[col] + lb[col];
                    if (yf) yf[(size_t)row*128 + col] = o;
                    if (yb) yb[(size_t)row*128 + col] = __float2bfloat16(o);
                }
            }
        }
    }
}

// ---------------- per-node online-softmax attention ----------------
// qb: [N][128] bf16 ; kvb: [N][256] bf16 interleaved {k2l,k2l+1,v2l,v2l+1} per lane l
__global__ __launch_bounds__(256) void k_attn(const __hip_bfloat16* __restrict__ qb,
                                              const __hip_bfloat16* __restrict__ kvb,
                                              const int* __restrict__ off,
                                              const int* __restrict__ csr_src,
                                              __hip_bfloat16* __restrict__ a, int N){
    int wid = (blockIdx.x*blockDim.x + threadIdx.x) >> 6;
    int lane = threadIdx.x & 63;
    if (wid >= N) return;
    ushort2 qu = ((const ushort2*)qb)[(size_t)wid*64 + lane];
    float qx = bf2f(qu.x), qy = bf2f(qu.y);
    const ushort4* kv = (const ushort4*)kvb;
    int beg = off[wid], end = off[wid+1];
    float m = -INFINITY, dsum = 0.f, ax = 0.f, ay = 0.f;
    for (int e0 = beg; e0 < end; e0 += 64){
        int myidx = (e0 + lane < end) ? csr_src[e0 + lane] : 0;
        int cnt = min(64, end - e0);
        int j = 0;
        for (; j + 3 < cnt; j += 4){
            int s0 = __shfl(myidx, j);
            int s1 = __shfl(myidx, j+1);
            int s2 = __shfl(myidx, j+2);
            int s3 = __shfl(myidx, j+3);
            ushort4 u0 = kv[(size_t)s0*64 + lane];
            ushort4 u1 = kv[(size_t)s1*64 + lane];
            ushort4 u2 = kv[(size_t)s2*64 + lane];
            ushort4 u3 = kv[(size_t)s3*64 + lane];
            float p0 = qx*bf2f(u0.x) + qy*bf2f(u0.y);
            float p1 = qx*bf2f(u1.x) + qy*bf2f(u1.y);
            float p2 = qx*bf2f(u2.x) + qy*bf2f(u2.y);
            float p3 = qx*bf2f(u3.x) + qy*bf2f(u3.y);
            #pragma unroll
            for (int o = 1; o < 8; o <<= 1){
                p0 += __shfl_xor(p0, o);
                p1 += __shfl_xor(p1, o);
                p2 += __shfl_xor(p2, o);
                p3 += __shfl_xor(p3, o);
            }
            float es0 = p0*0.25f, es1 = p1*0.25f, es2 = p2*0.25f, es3 = p3*0.25f;
            float nm = fmaxf(fmaxf(m, fmaxf(es0, es1)), fmaxf(es2, es3));
            float sc = __expf(m - nm);
            float w0 = __expf(es0 - nm), w1 = __expf(es1 - nm);
            float w2 = __expf(es2 - nm), w3 = __expf(es3 - nm);
            dsum = dsum*sc + ((w0+w1) + (w2+w3));
            ax = ax*sc + w0*bf2f(u0.z) + w1*bf2f(u1.z) + w2*bf2f(u2.z) + w3*bf2f(u3.z);
            ay = ay*sc + w0*bf2f(u0.w) + w1*bf2f(u1.w) + w2*bf2f(u2.w) + w3*bf2f(u3.w);
            m = nm;
        }
        for (; j < cnt; ++j){
            int s = __shfl(myidx, j);
            ushort4 u = kv[(size_t)s*64 + lane];
            float p = qx*bf2f(u.x) + qy*bf2f(u.y);
            #pragma unroll
            for (int o = 1; o < 8; o <<= 1) p += __shfl_xor(p, o);
            float es = p*0.25f;
            float nm = fmaxf(m, es);
            float sc = __expf(m - nm);
            float w  = __expf(es - nm);
            dsum = dsum*sc + w;
            ax = ax*sc + w*bf2f(u.z);
            ay = ay*sc + w*bf2f(u.w);
            m = nm;
        }
    }
    float r = (dsum > 0.f) ? 1.f/dsum : 0.f;
    __hip_bfloat162 o2;
    o2.x = __float2bfloat16(ax*r);
    o2.y = __float2bfloat16(ay*r);
    ((__hip_bfloat162*)(a + (size_t)wid*D))[lane] = o2;
}

extern "C" void kernel_launch(void* const* d_in, const int* in_sizes, int n_in,
                              void* d_out, int out_size, void* d_ws, size_t ws_size,
                              hipStream_t stream){
    const float* h    = (const float*)d_in[0];
    const int*   src  = (const int*)  d_in[1];
    const int*   dst  = (const int*)  d_in[2];
    const float* Wq   = (const float*)d_in[3];
    const float* Wk   = (const float*)d_in[4];
    const float* Wv   = (const float*)d_in[5];
    const float* Wo   = (const float*)d_in[6];
    const float* ln1g = (const float*)d_in[7];
    const float* ln1b = (const float*)d_in[8];
    const float* ln2g = (const float*)d_in[9];
    const float* ln2b = (const float*)d_in[10];
    const float* W1   = (const float*)d_in[11];
    const float* b1   = (const float*)d_in[12];
    const float* W2   = (const float*)d_in[13];
    const float* b2   = (const float*)d_in[14];
    float* out = (float*)d_out;

    const int N = in_sizes[0] / D;
    const int E = in_sizes[1];

    char* ws = (char*)d_ws;
    size_t o = 0;
    const size_t row_bf = align256((size_t)N * D * sizeof(__hip_bfloat16));    // 12.8 MB
    const size_t kv_bf  = align256((size_t)N * 256 * sizeof(__hip_bfloat16));  // 25.6 MB
    const size_t row_f  = align256((size_t)N * D * sizeof(float));             // 25.6 MB

    __hip_bfloat16* qb  = (__hip_bfloat16*)(ws + o); o += row_bf;
    __hip_bfloat16* kvb = (__hip_bfloat16*)(ws + o); o += kv_bf;
    __hip_bfloat16* ab  = (__hip_bfloat16*)(ws + o); o += row_bf;
    __hip_bfloat16* t1b = qb;   // [N][512] bf16 overlays qb+kvb+ab (51.2MB) after Wo+LN1
    __hip_bfloat16* hb  = (__hip_bfloat16*)(ws + o); o += row_bf;
    __hip_bfloat16* h1b = hb;   // overlays hb after QKV GEMM
    float* h1f = (float*)(ws + o); o += row_f;
    __hip_bfloat16* Wqkvt = (__hip_bfloat16*)(ws + o); o += align256(384*128*2);
    __hip_bfloat16* W1t   = (__hip_bfloat16*)(ws + o); o += align256(512*128*2);
    __hip_bfloat16* W2t   = (__hip_bfloat16*)(ws + o); o += align256(128*512*2);
    __hip_bfloat16* Wot   = (__hip_bfloat16*)(ws + o); o += align256(128*128*2);
    int* cnt   = (int*)(ws + o); o += align256((size_t)N*4);
    int* cur   = (int*)(ws + o); o += align256((size_t)N*4);
    int* offp  = (int*)(ws + o); o += align256((size_t)(N+1)*4);
    int* bsum  = (int*)(ws + o); o += align256(1024*4);
    int* ebase = (int*)(ws + o); o += align256(1024*4);
    int* csr   = (int*)(ws + o); o += align256((size_t)E*4);

    const int NB = (N + 255)/256;   // 196

    // --- prep + CSR build ---
    (void)hipMemsetAsync(cnt, 0, (size_t)N*4, stream);
    k_count<<<1024, 256, 0, stream>>>(dst, E, cnt, N);

    k_cast<<<(N*D/4 + 255)/256, 256, 0, stream>>>(h, hb, N*D/4);
    k_prep_w<<<(128*128 + 255)/256, 256, 0, stream>>>(Wq, Wqkvt,           128, 128);
    k_prep_w<<<(128*128 + 255)/256, 256, 0, stream>>>(Wk, Wqkvt + 128*128, 128, 128);
    k_prep_w<<<(128*128 + 255)/256, 256, 0, stream>>>(Wv, Wqkvt + 256*128, 128, 128);
    k_prep_w<<<(128*128 + 255)/256, 256, 0, stream>>>(Wo, Wot, 128, 128);
    k_prep_w<<<(512*128 + 255)/256, 256, 0, stream>>>(W1, W1t, 128, 512);
    k_prep_w<<<(512*128 + 255)/256, 256, 0, stream>>>(W2, W2t, 512, 128);

    k_bsum <<<NB, 256, 0, stream>>>(cnt, N, bsum);
    k_scanb<<<1, 1024, 0, stream>>>(bsum, NB, ebase, offp, N);
    k_off  <<<NB, 256, 0, stream>>>(cnt, N, ebase, offp, cur);
    k_scatter<<<1024, 256, 0, stream>>>(src, dst, E, cur, csr, N);

    int mb = (N + BM - 1)/BM;   // 391

    // --- QKV projection (scatter epilogue: q + interleaved kv) ---
    k_gemm<1><<<dim3(mb,3), 256, 0, stream>>>(hb, Wqkvt, N, 384, 128,
        nullptr, 0, nullptr, qb, kvb, nullptr, nullptr, nullptr, nullptr, nullptr);

    // --- sparse attention ---
    k_attn<<<(N*64 + 255)/256, 256, 0, stream>>>(qb, kvb, offp, csr, ab, N);

    // --- Wo projection + residual(h) + LN1 -> h1f, h1b ---
    k_gemm<2><<<dim3(mb,1), 256, 0, stream>>>(ab, Wot, N, 128, 128,
        nullptr, 0, nullptr, nullptr, nullptr, h, ln1g, ln1b, h1f, h1b);

    // --- FFN1: relu(h1b @ W1 + b1) -> t1b ---
    k_gemm<0><<<dim3(mb,4), 256, 0, stream>>>(h1b, W1t, N, 512, 128,
        b1, 1, t1b, nullptr, nullptr, nullptr, nullptr, nullptr, nullptr, nullptr);

    // --- FFN2 + residual(h1f) + LN2 -> out ---
    k_gemm<2><<<dim3(mb,1), 256, 0, stream>>>(t1b, W2t, N, 128, 512,
        b2, 0, nullptr, nullptr, nullptr, h1f, ln2g, ln2b, out, nullptr);
}

// Round 6
// 383.988 us; speedup vs baseline: 2.4837x; 1.0881x over previous
//
#include <hip/hip_runtime.h>
#include <hip/hip_bf16.h>
#include <math.h>

#define D   128
#define FFD 512
#define NPART 8

typedef __attribute__((ext_vector_type(8))) short bf16x8;
typedef __attribute__((ext_vector_type(4))) float f32x4;

static inline size_t align256(size_t x){ return (x + 255) & ~(size_t)255; }

__device__ __forceinline__ float bf2f(unsigned short u){
    union { unsigned int i; float f; } x; x.i = ((unsigned int)u) << 16; return x.f;
}
__device__ __forceinline__ unsigned short f2bf(float f){
    return __builtin_bit_cast(unsigned short, __float2bfloat16(f));
}

// DPP butterfly add over 8-lane groups (no DS pipe): xor1, xor2, xor7(half-mirror)
#define DPP_ADD(x, ctrl) do { \
    int yi_ = __builtin_amdgcn_update_dpp(0, __builtin_bit_cast(int, x), ctrl, 0xf, 0xf, true); \
    x += __builtin_bit_cast(float, yi_); } while(0)

// ---------------- CSR build ----------------
__global__ __launch_bounds__(256) void k_count(const int* __restrict__ dst, int E,
                                               int* __restrict__ cnt){
    int i = blockIdx.x*blockDim.x + threadIdx.x;
    int stride = gridDim.x*blockDim.x;
    for (; i < E; i += stride) atomicAdd(&cnt[dst[i]], 1);
}

__global__ __launch_bounds__(256) void k_bsum(const int* __restrict__ cnt, int N,
                                              int* __restrict__ bsum){
    int id = blockIdx.x*256 + threadIdx.x;
    int v = (id < N) ? cnt[id] : 0;
    #pragma unroll
    for (int o = 1; o < 64; o <<= 1) v += __shfl_xor(v, o);
    __shared__ int w4[4];
    if ((threadIdx.x & 63) == 0) w4[threadIdx.x >> 6] = v;
    __syncthreads();
    if (threadIdx.x == 0) bsum[blockIdx.x] = w4[0] + w4[1] + w4[2] + w4[3];
}

__global__ __launch_bounds__(1024) void k_scanb(const int* __restrict__ bsum, int NB,
                                                int* __restrict__ ebase,
                                                int* __restrict__ off, int N){
    __shared__ int sh[1024];
    int tid = threadIdx.x;
    int v = (tid < NB) ? bsum[tid] : 0;
    sh[tid] = v; __syncthreads();
    for (int o = 1; o < 1024; o <<= 1){
        int t = (tid >= o) ? sh[tid-o] : 0;
        __syncthreads();
        sh[tid] += t;
        __syncthreads();
    }
    if (tid < NB) ebase[tid] = sh[tid] - v;
    if (tid == NB-1) off[N] = sh[tid];
}

__global__ __launch_bounds__(256) void k_off(const int* __restrict__ cnt, int N,
                                             const int* __restrict__ ebase,
                                             int* __restrict__ off, int* __restrict__ cur){
    __shared__ int sh[256];
    int tid = threadIdx.x;
    int id = blockIdx.x*256 + tid;
    int v = (id < N) ? cnt[id] : 0;
    sh[tid] = v; __syncthreads();
    for (int o = 1; o < 256; o <<= 1){
        int t = (tid >= o) ? sh[tid-o] : 0;
        __syncthreads();
        sh[tid] += t;
        __syncthreads();
    }
    int excl = sh[tid] - v;
    int base = ebase[blockIdx.x];
    if (id < N){ off[id] = base + excl; cur[id] = base + excl; }
}

// XCD-partitioned scatter: part p only handles dst in its N/8 slice so the csr
// slice (~800KB) stays in one XCD's L2 -> full lines before eviction.
__global__ __launch_bounds__(256) void k_scatter(const int* __restrict__ src,
                                                 const int* __restrict__ dst, int E,
                                                 int* __restrict__ cur,
                                                 int* __restrict__ csr_src, int N){
    int part = blockIdx.x & (NPART-1);
    int lo = (int)((long long)part     * N / NPART);
    int hi = (int)((long long)(part+1) * N / NPART);
    int stride = (gridDim.x >> 3) * 256;
    for (int i = (blockIdx.x >> 3)*256 + threadIdx.x; i < E; i += stride){
        int d = dst[i];
        if (d >= lo && d < hi){
            int p = atomicAdd(&cur[d], 1);
            csr_src[p] = src[i];
        }
    }
}

// ---------------- prep ----------------
__global__ __launch_bounds__(256) void k_cast(const float* __restrict__ x,
                                              __hip_bfloat16* __restrict__ y, int n4){
    int i = blockIdx.x*blockDim.x + threadIdx.x;
    if (i >= n4) return;
    float4 f = ((const float4*)x)[i];
    ushort4 u;
    u.x = f2bf(f.x); u.y = f2bf(f.y);
    u.z = f2bf(f.z); u.w = f2bf(f.w);
    ((ushort4*)y)[i] = u;
}

// merged weight transpose+cast: y selects which weight
__global__ __launch_bounds__(256) void k_prep_all(
    const float* __restrict__ Wq, const float* __restrict__ Wk,
    const float* __restrict__ Wv, const float* __restrict__ Wo,
    const float* __restrict__ W1, const float* __restrict__ W2,
    __hip_bfloat16* __restrict__ Wqkvt, __hip_bfloat16* __restrict__ Wot,
    __hip_bfloat16* __restrict__ W1t,   __hip_bfloat16* __restrict__ W2t){
    const float* W; __hip_bfloat16* Wt; int K, Nc;
    switch (blockIdx.y){
        case 0: W = Wq; Wt = Wqkvt;           K = 128; Nc = 128; break;
        case 1: W = Wk; Wt = Wqkvt + 128*128; K = 128; Nc = 128; break;
        case 2: W = Wv; Wt = Wqkvt + 256*128; K = 128; Nc = 128; break;
        case 3: W = Wo; Wt = Wot;             K = 128; Nc = 128; break;
        case 4: W = W1; Wt = W1t;             K = 128; Nc = 512; break;
        default: W = W2; Wt = W2t;            K = 512; Nc = 128; break;
    }
    int total = K*Nc;
    for (int id = blockIdx.x*256 + threadIdx.x; id < total; id += 256*gridDim.x){
        int n = id / K, kk = id % K;
        Wt[id] = __float2bfloat16(W[(size_t)kk*Nc + n]);
    }
}

// ---------------- MFMA bf16 GEMM, templated epilogue ----------------
// MODE 0: bias/relu -> bf16 C [M][Nc]
// MODE 1: QKV scatter: region 0 -> qb[N][128], 1/2 -> kvb interleaved [N][256]
// MODE 2: bias + f32 residual + LayerNorm -> yb bf16
// MODE 3: bias + bf16 residual + LayerNorm -> yf f32
#define BM 128
#define BN 128
#define BK 64

// XCD-aware tile swizzle: grid = dim3(ncols, mb_pad) with mb_pad % 8 == 0.
// All ncols column-tiles of a row-tile land on the SAME XCD (f differs by 8),
// so the shared A row-tile is fetched into that XCD's L2 once.
__device__ __forceinline__ bool tile_coords(int M, int &r0, int &c0){
    int ncols = gridDim.x;
    int f = blockIdx.y * ncols + blockIdx.x;
    int xcd = f & 7, s = f >> 3;
    int c = s % ncols, rl = s / ncols;
    int r = rl*8 + xcd;
    r0 = r*BM; c0 = c*BN;
    return r0 < M;
}

__device__ __forceinline__ void stage_tile(const __hip_bfloat16* __restrict__ src,
                                           int row_base, int row_limit, int K, int k0,
                                           __hip_bfloat16* lds){
    int tid = threadIdx.x;
    int wave = tid >> 6;
    #pragma unroll
    for (int i = 0; i < 4; ++i){
        int c = i*256 + tid;          // 16B chunk: 1024 chunks = 128 rows x 8 slots
        int r = c >> 3, s = c & 7;
        int sg = s ^ (r & 7);         // inverse swizzle on source
        int gr = row_base + r; if (gr >= row_limit) gr = row_limit - 1;
        const __hip_bfloat16* gp = src + (size_t)gr*K + k0 + sg*8;
        char* lp = (char*)lds + (i*256 + wave*64)*16;   // wave-uniform base
        __builtin_amdgcn_global_load_lds((const __attribute__((address_space(1))) void*)gp,
                                         (__attribute__((address_space(3))) void*)lp,
                                         16, 0, 0);
    }
}

template<int MODE>
__global__ __launch_bounds__(256) void k_gemm(
    const __hip_bfloat16* __restrict__ A,   // [M][K]
    const __hip_bfloat16* __restrict__ Bt,  // [Nc][K]
    int M, int Nc, int K,
    const float* __restrict__ bias, int relu,
    __hip_bfloat16* __restrict__ Cb,                                    // MODE 0
    __hip_bfloat16* __restrict__ qb, __hip_bfloat16* __restrict__ kvb,  // MODE 1
    const float* __restrict__ resid_f, const __hip_bfloat16* __restrict__ resid_b,
    const float* __restrict__ lg, const float* __restrict__ lb,
    float* __restrict__ yf, __hip_bfloat16* __restrict__ yb){           // MODE 2/3
    __shared__ __hip_bfloat16 As[BM*BK];
    __shared__ __hip_bfloat16 Bs[BN*BK];
    __shared__ float red[2][BM][2];
    int r0, c0;
    if (!tile_coords(M, r0, c0)) return;
    int tid = threadIdx.x;
    int lane = tid & 63, wave = tid >> 6;
    int wr = wave >> 1, wc = wave & 1;
    int lr = lane & 15, ls = lane >> 4;

    f32x4 acc[4][4];
    #pragma unroll
    for (int m = 0; m < 4; m++)
        #pragma unroll
        for (int n = 0; n < 4; n++) acc[m][n] = (f32x4){0.f,0.f,0.f,0.f};

    for (int k0 = 0; k0 < K; k0 += BK){
        stage_tile(A,  r0, M,  K, k0, As);
        stage_tile(Bt, c0, Nc, K, k0, Bs);
        __syncthreads();
        #pragma unroll
        for (int kk = 0; kk < 2; ++kk){
            bf16x8 af[4], bfg[4];
            #pragma unroll
            for (int m = 0; m < 4; m++){
                int R = wr*64 + m*16 + lr;
                int sl = (kk*4 + ls) ^ (R & 7);
                af[m] = *(const bf16x8*)((const char*)As + R*128 + sl*16);
            }
            #pragma unroll
            for (int n = 0; n < 4; n++){
                int R = wc*64 + n*16 + lr;
                int sl = (kk*4 + ls) ^ (R & 7);
                bfg[n] = *(const bf16x8*)((const char*)Bs + R*128 + sl*16);
            }
            #pragma unroll
            for (int m = 0; m < 4; m++)
                #pragma unroll
                for (int n = 0; n < 4; n++)
                    acc[m][n] = __builtin_amdgcn_mfma_f32_16x16x32_bf16(af[m], bfg[n], acc[m][n], 0, 0, 0);
        }
        __syncthreads();
    }

    // C/D layout: col=lane&15, row=(lane>>4)*4+reg
    if (MODE == 0){
        #pragma unroll
        for (int n = 0; n < 4; n++){
            int col = c0 + wc*64 + n*16 + lr;
            float bval = bias ? bias[col] : 0.f;
            #pragma unroll
            for (int m = 0; m < 4; m++){
                #pragma unroll
                for (int j = 0; j < 4; j++){
                    int row = r0 + wr*64 + m*16 + ls*4 + j;
                    if (row >= M) continue;
                    float v = acc[m][n][j] + bval;
                    if (relu) v = fmaxf(v, 0.f);
                    Cb[(size_t)row*Nc + col] = __float2bfloat16(v);
                }
            }
        }
    } else if (MODE == 1){
        int region = c0 >> 7;    // 0=q, 1=k, 2=v
        #pragma unroll
        for (int n = 0; n < 4; n++){
            int c16 = wc*64 + n*16 + lr;
            #pragma unroll
            for (int m = 0; m < 4; m++){
                #pragma unroll
                for (int j = 0; j < 4; j++){
                    int row = r0 + wr*64 + m*16 + ls*4 + j;
                    if (row >= M) continue;
                    unsigned short v = f2bf(acc[m][n][j]);
                    if (region == 0)
                        ((unsigned short*)qb)[(size_t)row*128 + c16] = v;
                    else if (region == 1)
                        ((unsigned short*)kvb)[(size_t)row*256 + (c16>>1)*4 + (c16&1)] = v;
                    else
                        ((unsigned short*)kvb)[(size_t)row*256 + (c16>>1)*4 + 2 + (c16&1)] = v;
                }
            }
        }
    } else {
        #pragma unroll
        for (int m = 0; m < 4; m++){
            #pragma unroll
            for (int j = 0; j < 4; j++){
                int row = r0 + wr*64 + m*16 + ls*4 + j;
                float s = 0.f, q = 0.f;
                if (row < M){
                    #pragma unroll
                    for (int n = 0; n < 4; n++){
                        int col = wc*64 + n*16 + lr;
                        float bval = bias ? bias[col] : 0.f;
                        float rv = (MODE == 2) ? resid_f[(size_t)row*128 + col]
                                               : bf2f(((const unsigned short*)resid_b)[(size_t)row*128 + col]);
                        float v = acc[m][n][j] + bval + rv;
                        acc[m][n][j] = v;
                        s += v; q += v*v;
                    }
                }
                #pragma unroll
                for (int o = 1; o < 16; o <<= 1){
                    s += __shfl_xor(s, o);
                    q += __shfl_xor(q, o);
                }
                if (lr == 0 && row < M){
                    int rloc = wr*64 + m*16 + ls*4 + j;
                    red[0][rloc][wc] = s;
                    red[1][rloc][wc] = q;
                }
            }
        }
        __syncthreads();
        #pragma unroll
        for (int m = 0; m < 4; m++){
            #pragma unroll
            for (int j = 0; j < 4; j++){
                int rloc = wr*64 + m*16 + ls*4 + j;
                int row = r0 + rloc;
                if (row >= M) continue;
                float mu  = (red[0][rloc][0] + red[0][rloc][1]) * (1.f/128.f);
                float eq  = (red[1][rloc][0] + red[1][rloc][1]) * (1.f/128.f);
                float var = fmaxf(eq - mu*mu, 0.f);
                float inv = rsqrtf(var + 1e-5f);
                #pragma unroll
                for (int n = 0; n < 4; n++){
                    int col = wc*64 + n*16 + lr;
                    float o = (acc[m][n][j] - mu)*inv*lg[col] + lb[col];
                    if (MODE == 3) yf[(size_t)row*128 + col] = o;
                    else           yb[(size_t)row*128 + col] = __float2bfloat16(o);
                }
            }
        }
    }
}

// ---------------- per-node attention: no-max softmax, DPP reduce, readlane bcast ----
// Scores bounded (|e| <= ~30) so exp2 in f32 never overflows; sums commute, so no
// online max/rescale chain. q prescaled by log2e/sqrt(dk).
#define EDGE(u, dd, axx, ayy) { \
    int s_ = __builtin_amdgcn_readlane(myidx, j+(u)); \
    ushort4 uu = kv[(size_t)(unsigned)s_*64 + lane]; \
    float p_ = qx*bf2f(uu.x) + qy*bf2f(uu.y); \
    DPP_ADD(p_, 0xB1); DPP_ADD(p_, 0x4E); DPP_ADD(p_, 0x141); \
    float w_ = __builtin_amdgcn_exp2f(p_); \
    dd += w_; axx = fmaf(w_, bf2f(uu.z), axx); ayy = fmaf(w_, bf2f(uu.w), ayy); }

__global__ __launch_bounds__(256) void k_attn(const __hip_bfloat16* __restrict__ qb,
                                              const __hip_bfloat16* __restrict__ kvb,
                                              const int* __restrict__ off,
                                              const int* __restrict__ csr_src,
                                              __hip_bfloat16* __restrict__ a, int N){
    int wid = (blockIdx.x*blockDim.x + threadIdx.x) >> 6;
    int lane = threadIdx.x & 63;
    if (wid >= N) return;
    ushort2 qu = ((const ushort2*)qb)[(size_t)wid*64 + lane];
    const float SC = 0.25f * 1.44269504f;   // log2e / sqrt(16)
    float qx = bf2f(qu.x)*SC, qy = bf2f(qu.y)*SC;
    const ushort4* kv = (const ushort4*)kvb;
    int beg = off[wid], end = off[wid+1];
    float d0 = 0.f, d1 = 0.f, ax0 = 0.f, ay0 = 0.f, ax1 = 0.f, ay1 = 0.f;
    for (int e0 = beg; e0 < end; e0 += 64){
        int myidx = (e0 + lane < end) ? csr_src[e0 + lane] : 0;
        int cnt = min(64, end - e0);
        int j = 0;
        for (; j + 7 < cnt; j += 8){
            EDGE(0, d0, ax0, ay0); EDGE(1, d1, ax1, ay1);
            EDGE(2, d0, ax0, ay0); EDGE(3, d1, ax1, ay1);
            EDGE(4, d0, ax0, ay0); EDGE(5, d1, ax1, ay1);
            EDGE(6, d0, ax0, ay0); EDGE(7, d1, ax1, ay1);
        }
        for (; j < cnt; ++j){
            EDGE(0, d0, ax0, ay0);
        }
    }
    float dsum = d0 + d1;
    float r = (dsum > 0.f) ? 1.f/dsum : 0.f;
    __hip_bfloat162 o2;
    o2.x = __float2bfloat16((ax0 + ax1)*r);
    o2.y = __float2bfloat16((ay0 + ay1)*r);
    ((__hip_bfloat162*)(a + (size_t)wid*D))[lane] = o2;
}

extern "C" void kernel_launch(void* const* d_in, const int* in_sizes, int n_in,
                              void* d_out, int out_size, void* d_ws, size_t ws_size,
                              hipStream_t stream){
    const float* h    = (const float*)d_in[0];
    const int*   src  = (const int*)  d_in[1];
    const int*   dst  = (const int*)  d_in[2];
    const float* Wq   = (const float*)d_in[3];
    const float* Wk   = (const float*)d_in[4];
    const float* Wv   = (const float*)d_in[5];
    const float* Wo   = (const float*)d_in[6];
    const float* ln1g = (const float*)d_in[7];
    const float* ln1b = (const float*)d_in[8];
    const float* ln2g = (const float*)d_in[9];
    const float* ln2b = (const float*)d_in[10];
    const float* W1   = (const float*)d_in[11];
    const float* b1   = (const float*)d_in[12];
    const float* W2   = (const float*)d_in[13];
    const float* b2   = (const float*)d_in[14];
    float* out = (float*)d_out;

    const int N = in_sizes[0] / D;
    const int E = in_sizes[1];

    char* ws = (char*)d_ws;
    size_t o = 0;
    const size_t row_bf = align256((size_t)N * D * sizeof(__hip_bfloat16));    // 12.8 MB
    const size_t kv_bf  = align256((size_t)N * 256 * sizeof(__hip_bfloat16));  // 25.6 MB

    __hip_bfloat16* qb  = (__hip_bfloat16*)(ws + o); o += row_bf;
    __hip_bfloat16* kvb = (__hip_bfloat16*)(ws + o); o += kv_bf;
    __hip_bfloat16* ab  = (__hip_bfloat16*)(ws + o); o += row_bf;
    __hip_bfloat16* t1b = qb;   // [N][512] bf16 overlays qb+kvb+ab after attention
    __hip_bfloat16* hb  = (__hip_bfloat16*)(ws + o); o += row_bf;
    __hip_bfloat16* h1b = hb;   // overlays hb after QKV GEMM
    __hip_bfloat16* Wqkvt = (__hip_bfloat16*)(ws + o); o += align256(384*128*2);
    __hip_bfloat16* W1t   = (__hip_bfloat16*)(ws + o); o += align256(512*128*2);
    __hip_bfloat16* W2t   = (__hip_bfloat16*)(ws + o); o += align256(128*512*2);
    __hip_bfloat16* Wot   = (__hip_bfloat16*)(ws + o); o += align256(128*128*2);
    int* cnt   = (int*)(ws + o); o += align256((size_t)N*4);
    int* cur   = (int*)(ws + o); o += align256((size_t)N*4);
    int* offp  = (int*)(ws + o); o += align256((size_t)(N+1)*4);
    int* bsum  = (int*)(ws + o); o += align256(1024*4);
    int* ebase = (int*)(ws + o); o += align256(1024*4);
    int* csr   = (int*)(ws + o); o += align256((size_t)E*4);

    const int NB = (N + 255)/256;   // 196

    // --- prep + CSR build ---
    (void)hipMemsetAsync(cnt, 0, (size_t)N*4, stream);
    k_count<<<min((E + 255)/256, 4096), 256, 0, stream>>>(dst, E, cnt);
    k_cast<<<(N*D/4 + 255)/256, 256, 0, stream>>>(h, hb, N*D/4);
    k_prep_all<<<dim3(64, 6), 256, 0, stream>>>(Wq, Wk, Wv, Wo, W1, W2,
                                                Wqkvt, Wot, W1t, W2t);
    k_bsum <<<NB, 256, 0, stream>>>(cnt, N, bsum);
    k_scanb<<<1, 1024, 0, stream>>>(bsum, NB, ebase, offp, N);
    k_off  <<<NB, 256, 0, stream>>>(cnt, N, ebase, offp, cur);
    k_scatter<<<1024, 256, 0, stream>>>(src, dst, E, cur, csr, N);

    int mb = (N + BM - 1)/BM;            // 391
    int mb_pad = ((mb + 7)/8)*8;         // 392

    // --- QKV projection (scatter epilogue: q + interleaved kv) ---
    k_gemm<1><<<dim3(3, mb_pad), 256, 0, stream>>>(hb, Wqkvt, N, 384, 128,
        nullptr, 0, nullptr, qb, kvb, nullptr, nullptr, nullptr, nullptr, nullptr, nullptr);

    // --- sparse attention ---
    k_attn<<<(N*64 + 255)/256, 256, 0, stream>>>(qb, kvb, offp, csr, ab, N);

    // --- Wo projection + residual(h, f32) + LN1 -> h1b (bf16) ---
    k_gemm<2><<<dim3(1, mb_pad), 256, 0, stream>>>(ab, Wot, N, 128, 128,
        nullptr, 0, nullptr, nullptr, nullptr, h, nullptr, ln1g, ln1b, nullptr, h1b);

    // --- FFN1: relu(h1b @ W1 + b1) -> t1b ---
    k_gemm<0><<<dim3(4, mb_pad), 256, 0, stream>>>(h1b, W1t, N, 512, 128,
        b1, 1, t1b, nullptr, nullptr, nullptr, nullptr, nullptr, nullptr, nullptr, nullptr);

    // --- FFN2 + residual(h1b, bf16) + LN2 -> out (f32) ---
    k_gemm<3><<<dim3(1, mb_pad), 256, 0, stream>>>(t1b, W2t, N, 128, 512,
        b2, 0, nullptr, nullptr, nullptr, nullptr, h1b, ln2g, ln2b, out, nullptr);
}

// Round 7
// 331.936 us; speedup vs baseline: 2.8732x; 1.1568x over previous
//
#include <hip/hip_runtime.h>
#include <hip/hip_bf16.h>
#include <math.h>

#define D   128
#define FFD 512
#define NPART 8

typedef __attribute__((ext_vector_type(8))) short bf16x8;
typedef __attribute__((ext_vector_type(4))) float f32x4;
typedef __attribute__((ext_vector_type(2))) float f32x2;

static inline size_t align256(size_t x){ return (x + 255) & ~(size_t)255; }

__device__ __forceinline__ float bf2f(unsigned short u){
    union { unsigned int i; float f; } x; x.i = ((unsigned int)u) << 16; return x.f;
}
__device__ __forceinline__ unsigned short f2bf(float f){
    return __builtin_bit_cast(unsigned short, __float2bfloat16(f));
}
// single fp8 e4m3 encode (OCP on gfx950)
__device__ __forceinline__ unsigned char f2fp8(float f){
    return (unsigned char)(__builtin_amdgcn_cvt_pk_fp8_f32(f, f, 0, false) & 0xff);
}

// DPP butterfly add over 8-lane groups (no DS pipe): xor1, xor2, half-mirror
#define DPP_ADD(x, ctrl) do { \
    int yi_ = __builtin_amdgcn_update_dpp(0, __builtin_bit_cast(int, x), ctrl, 0xf, 0xf, true); \
    x += __builtin_bit_cast(float, yi_); } while(0)

// ---------------- CSR build ----------------
__global__ __launch_bounds__(256) void k_count(const int* __restrict__ dst, int E,
                                               int* __restrict__ cnt){
    int i = blockIdx.x*blockDim.x + threadIdx.x;
    int stride = gridDim.x*blockDim.x;
    for (; i < E; i += stride) atomicAdd(&cnt[dst[i]], 1);
}

__global__ __launch_bounds__(256) void k_bsum(const int* __restrict__ cnt, int N,
                                              int* __restrict__ bsum){
    int id = blockIdx.x*256 + threadIdx.x;
    int v = (id < N) ? cnt[id] : 0;
    #pragma unroll
    for (int o = 1; o < 64; o <<= 1) v += __shfl_xor(v, o);
    __shared__ int w4[4];
    if ((threadIdx.x & 63) == 0) w4[threadIdx.x >> 6] = v;
    __syncthreads();
    if (threadIdx.x == 0) bsum[blockIdx.x] = w4[0] + w4[1] + w4[2] + w4[3];
}

__global__ __launch_bounds__(1024) void k_scanb(const int* __restrict__ bsum, int NB,
                                                int* __restrict__ ebase,
                                                int* __restrict__ off, int N){
    __shared__ int sh[1024];
    int tid = threadIdx.x;
    int v = (tid < NB) ? bsum[tid] : 0;
    sh[tid] = v; __syncthreads();
    for (int o = 1; o < 1024; o <<= 1){
        int t = (tid >= o) ? sh[tid-o] : 0;
        __syncthreads();
        sh[tid] += t;
        __syncthreads();
    }
    if (tid < NB) ebase[tid] = sh[tid] - v;
    if (tid == NB-1) off[N] = sh[tid];
}

__global__ __launch_bounds__(256) void k_off(const int* __restrict__ cnt, int N,
                                             const int* __restrict__ ebase,
                                             int* __restrict__ off, int* __restrict__ cur){
    __shared__ int sh[256];
    int tid = threadIdx.x;
    int id = blockIdx.x*256 + tid;
    int v = (id < N) ? cnt[id] : 0;
    sh[tid] = v; __syncthreads();
    for (int o = 1; o < 256; o <<= 1){
        int t = (tid >= o) ? sh[tid-o] : 0;
        __syncthreads();
        sh[tid] += t;
        __syncthreads();
    }
    int excl = sh[tid] - v;
    int base = ebase[blockIdx.x];
    if (id < N){ off[id] = base + excl; cur[id] = base + excl; }
}

// XCD-partitioned scatter: part p only handles dst in its N/8 slice so the csr
// slice (~800KB) stays in one XCD's L2 -> full lines before eviction.
__global__ __launch_bounds__(256) void k_scatter(const int* __restrict__ src,
                                                 const int* __restrict__ dst, int E,
                                                 int* __restrict__ cur,
                                                 int* __restrict__ csr_src, int N){
    int part = blockIdx.x & (NPART-1);
    int lo = (int)((long long)part     * N / NPART);
    int hi = (int)((long long)(part+1) * N / NPART);
    int stride = (gridDim.x >> 3) * 256;
    for (int i = (blockIdx.x >> 3)*256 + threadIdx.x; i < E; i += stride){
        int d = dst[i];
        if (d >= lo && d < hi){
            int p = atomicAdd(&cur[d], 1);
            csr_src[p] = src[i];
        }
    }
}

// ---------------- prep ----------------
__global__ __launch_bounds__(256) void k_cast(const float* __restrict__ x,
                                              __hip_bfloat16* __restrict__ y, int n4){
    int i = blockIdx.x*blockDim.x + threadIdx.x;
    if (i >= n4) return;
    float4 f = ((const float4*)x)[i];
    ushort4 u;
    u.x = f2bf(f.x); u.y = f2bf(f.y);
    u.z = f2bf(f.z); u.w = f2bf(f.w);
    ((ushort4*)y)[i] = u;
}

// merged weight transpose+cast. For Wk/Wv the destination rows inside Wqkvt are
// interleaved {k2g,k2g+1,v2g,v2g+1} so that GEMM col-tile 1 emits bytes 0..127
// and tile 2 bytes 128..255 of each fp8 kv row (full-line writes per block).
__global__ __launch_bounds__(256) void k_prep_all(
    const float* __restrict__ Wq, const float* __restrict__ Wk,
    const float* __restrict__ Wv, const float* __restrict__ Wo,
    const float* __restrict__ W1, const float* __restrict__ W2,
    __hip_bfloat16* __restrict__ Wqkvt, __hip_bfloat16* __restrict__ Wot,
    __hip_bfloat16* __restrict__ W1t,   __hip_bfloat16* __restrict__ W2t){
    const float* W; __hip_bfloat16* Wt; int K, Nc;
    int y = blockIdx.y;
    switch (y){
        case 0: W = Wq; Wt = Wqkvt; K = 128; Nc = 128; break;
        case 1: W = Wk; Wt = Wqkvt; K = 128; Nc = 128; break;
        case 2: W = Wv; Wt = Wqkvt; K = 128; Nc = 128; break;
        case 3: W = Wo; Wt = Wot;   K = 128; Nc = 128; break;
        case 4: W = W1; Wt = W1t;   K = 128; Nc = 512; break;
        default: W = W2; Wt = W2t;  K = 512; Nc = 128; break;
    }
    int total = K*Nc;
    for (int id = blockIdx.x*256 + threadIdx.x; id < total; id += 256*gridDim.x){
        int n = id / K, kk = id % K;
        size_t drow;
        if (y == 1)      drow = 128 + ((n>>1)<<2) + (n&1);
        else if (y == 2) drow = 128 + ((n>>1)<<2) + 2 + (n&1);
        else             drow = n;
        Wt[drow*K + kk] = __float2bfloat16(W[(size_t)kk*Nc + n]);
    }
}

// ---------------- MFMA bf16 GEMM, templated epilogue ----------------
// MODE 0: bias/relu -> bf16 C [M][Nc]
// MODE 1: QKV: tile0 -> qb[N][128] bf16; tiles 1/2 -> fp8 kv row bytes [N][256]
// MODE 2: bias + f32 residual + LayerNorm -> yb bf16
// MODE 3: bias + bf16 residual + LayerNorm -> yf f32
#define BM 128
#define BN 128
#define BK 64

// XCD-aware tile swizzle: grid = dim3(ncols, mb_pad) with mb_pad % 8 == 0.
__device__ __forceinline__ bool tile_coords(int M, int &r0, int &c0){
    int ncols = gridDim.x;
    int f = blockIdx.y * ncols + blockIdx.x;
    int xcd = f & 7, s = f >> 3;
    int c = s % ncols, rl = s / ncols;
    int r = rl*8 + xcd;
    r0 = r*BM; c0 = c*BN;
    return r0 < M;
}

__device__ __forceinline__ void stage_tile(const __hip_bfloat16* __restrict__ src,
                                           int row_base, int row_limit, int K, int k0,
                                           __hip_bfloat16* lds){
    int tid = threadIdx.x;
    int wave = tid >> 6;
    #pragma unroll
    for (int i = 0; i < 4; ++i){
        int c = i*256 + tid;          // 16B chunk: 1024 chunks = 128 rows x 8 slots
        int r = c >> 3, s = c & 7;
        int sg = s ^ (r & 7);         // inverse swizzle on source
        int gr = row_base + r; if (gr >= row_limit) gr = row_limit - 1;
        const __hip_bfloat16* gp = src + (size_t)gr*K + k0 + sg*8;
        char* lp = (char*)lds + (i*256 + wave*64)*16;   // wave-uniform base
        __builtin_amdgcn_global_load_lds((const __attribute__((address_space(1))) void*)gp,
                                         (__attribute__((address_space(3))) void*)lp,
                                         16, 0, 0);
    }
}

template<int MODE>
__global__ __launch_bounds__(256) void k_gemm(
    const __hip_bfloat16* __restrict__ A,   // [M][K]
    const __hip_bfloat16* __restrict__ Bt,  // [Nc][K]
    int M, int Nc, int K,
    const float* __restrict__ bias, int relu,
    __hip_bfloat16* __restrict__ Cb,                                    // MODE 0
    __hip_bfloat16* __restrict__ qb, unsigned char* __restrict__ kvq,   // MODE 1
    const float* __restrict__ resid_f, const __hip_bfloat16* __restrict__ resid_b,
    const float* __restrict__ lg, const float* __restrict__ lb,
    float* __restrict__ yf, __hip_bfloat16* __restrict__ yb){           // MODE 2/3
    __shared__ __hip_bfloat16 As[BM*BK];
    __shared__ __hip_bfloat16 Bs[BN*BK];
    __shared__ float red[2][BM][2];
    int r0, c0;
    if (!tile_coords(M, r0, c0)) return;
    int tid = threadIdx.x;
    int lane = tid & 63, wave = tid >> 6;
    int wr = wave >> 1, wc = wave & 1;
    int lr = lane & 15, ls = lane >> 4;

    f32x4 acc[4][4];
    #pragma unroll
    for (int m = 0; m < 4; m++)
        #pragma unroll
        for (int n = 0; n < 4; n++) acc[m][n] = (f32x4){0.f,0.f,0.f,0.f};

    for (int k0 = 0; k0 < K; k0 += BK){
        stage_tile(A,  r0, M,  K, k0, As);
        stage_tile(Bt, c0, Nc, K, k0, Bs);
        __syncthreads();
        #pragma unroll
        for (int kk = 0; kk < 2; ++kk){
            bf16x8 af[4], bfg[4];
            #pragma unroll
            for (int m = 0; m < 4; m++){
                int R = wr*64 + m*16 + lr;
                int sl = (kk*4 + ls) ^ (R & 7);
                af[m] = *(const bf16x8*)((const char*)As + R*128 + sl*16);
            }
            #pragma unroll
            for (int n = 0; n < 4; n++){
                int R = wc*64 + n*16 + lr;
                int sl = (kk*4 + ls) ^ (R & 7);
                bfg[n] = *(const bf16x8*)((const char*)Bs + R*128 + sl*16);
            }
            #pragma unroll
            for (int m = 0; m < 4; m++)
                #pragma unroll
                for (int n = 0; n < 4; n++)
                    acc[m][n] = __builtin_amdgcn_mfma_f32_16x16x32_bf16(af[m], bfg[n], acc[m][n], 0, 0, 0);
        }
        __syncthreads();
    }

    // C/D layout: col=lane&15, row=(lane>>4)*4+reg
    if (MODE == 0){
        #pragma unroll
        for (int n = 0; n < 4; n++){
            int col = c0 + wc*64 + n*16 + lr;
            float bval = bias ? bias[col] : 0.f;
            #pragma unroll
            for (int m = 0; m < 4; m++){
                #pragma unroll
                for (int j = 0; j < 4; j++){
                    int row = r0 + wr*64 + m*16 + ls*4 + j;
                    if (row >= M) continue;
                    float v = acc[m][n][j] + bval;
                    if (relu) v = fmaxf(v, 0.f);
                    Cb[(size_t)row*Nc + col] = __float2bfloat16(v);
                }
            }
        }
    } else if (MODE == 1){
        int region = c0 >> 7;    // 0=q, 1=kv bytes 0..127, 2=kv bytes 128..255
        #pragma unroll
        for (int n = 0; n < 4; n++){
            int c16 = wc*64 + n*16 + lr;
            #pragma unroll
            for (int m = 0; m < 4; m++){
                #pragma unroll
                for (int j = 0; j < 4; j++){
                    int row = r0 + wr*64 + m*16 + ls*4 + j;
                    if (row >= M) continue;
                    float v = acc[m][n][j];
                    if (region == 0)
                        ((unsigned short*)qb)[(size_t)row*128 + c16] = f2bf(v);
                    else
                        kvq[(size_t)row*256 + (region-1)*128 + c16] = f2fp8(v);
                }
            }
        }
    } else {
        #pragma unroll
        for (int m = 0; m < 4; m++){
            #pragma unroll
            for (int j = 0; j < 4; j++){
                int row = r0 + wr*64 + m*16 + ls*4 + j;
                float s = 0.f, q = 0.f;
                if (row < M){
                    #pragma unroll
                    for (int n = 0; n < 4; n++){
                        int col = wc*64 + n*16 + lr;
                        float bval = bias ? bias[col] : 0.f;
                        float rv = (MODE == 2) ? resid_f[(size_t)row*128 + col]
                                               : bf2f(((const unsigned short*)resid_b)[(size_t)row*128 + col]);
                        float v = acc[m][n][j] + bval + rv;
                        acc[m][n][j] = v;
                        s += v; q += v*v;
                    }
                }
                #pragma unroll
                for (int o = 1; o < 16; o <<= 1){
                    s += __shfl_xor(s, o);
                    q += __shfl_xor(q, o);
                }
                if (lr == 0 && row < M){
                    int rloc = wr*64 + m*16 + ls*4 + j;
                    red[0][rloc][wc] = s;
                    red[1][rloc][wc] = q;
                }
            }
        }
        __syncthreads();
        #pragma unroll
        for (int m = 0; m < 4; m++){
            #pragma unroll
            for (int j = 0; j < 4; j++){
                int rloc = wr*64 + m*16 + ls*4 + j;
                int row = r0 + rloc;
                if (row >= M) continue;
                float mu  = (red[0][rloc][0] + red[0][rloc][1]) * (1.f/128.f);
                float eq  = (red[1][rloc][0] + red[1][rloc][1]) * (1.f/128.f);
                float var = fmaxf(eq - mu*mu, 0.f);
                float inv = rsqrtf(var + 1e-5f);
                #pragma unroll
                for (int n = 0; n < 4; n++){
                    int col = wc*64 + n*16 + lr;
                    float o = (acc[m][n][j] - mu)*inv*lg[col] + lb[col];
                    if (MODE == 3) yf[(size_t)row*128 + col] = o;
                    else           yb[(size_t)row*128 + col] = __float2bfloat16(o);
                }
            }
        }
    }
}

// ---------------- per-node attention: fp8 kv, no-max softmax, DPP reduce ----------
// kvq row (256B): uint per lane l = fp8 {k2l, k2l+1, v2l, v2l+1}
#define EDGE(u_, dd, axx, ayy) { \
    int s_ = __builtin_amdgcn_readlane(myidx, j+(u_)); \
    unsigned uu = kv[(size_t)(unsigned)s_*64 + lane]; \
    f32x2 kf = __builtin_amdgcn_cvt_pk_f32_fp8((int)uu, false); \
    f32x2 vf = __builtin_amdgcn_cvt_pk_f32_fp8((int)uu, true); \
    float p_ = qx*kf[0] + qy*kf[1]; \
    DPP_ADD(p_, 0xB1); DPP_ADD(p_, 0x4E); DPP_ADD(p_, 0x141); \
    float w_ = __builtin_amdgcn_exp2f(p_); \
    dd += w_; axx = fmaf(w_, vf[0], axx); ayy = fmaf(w_, vf[1], ayy); }

__global__ __launch_bounds__(256) void k_attn(const __hip_bfloat16* __restrict__ qb,
                                              const unsigned* __restrict__ kvq,
                                              const int* __restrict__ off,
                                              const int* __restrict__ csr_src,
                                              __hip_bfloat16* __restrict__ a, int N){
    int wid = (blockIdx.x*blockDim.x + threadIdx.x) >> 6;
    int lane = threadIdx.x & 63;
    if (wid >= N) return;
    ushort2 qu = ((const ushort2*)qb)[(size_t)wid*64 + lane];
    const float SC = 0.25f * 1.44269504f;   // log2e / sqrt(16)
    float qx = bf2f(qu.x)*SC, qy = bf2f(qu.y)*SC;
    const unsigned* kv = kvq;
    int beg = off[wid], end = off[wid+1];
    float d0 = 0.f, d1 = 0.f, ax0 = 0.f, ay0 = 0.f, ax1 = 0.f, ay1 = 0.f;
    for (int e0 = beg; e0 < end; e0 += 64){
        int myidx = (e0 + lane < end) ? csr_src[e0 + lane] : 0;
        int cnt = min(64, end - e0);
        int j = 0;
        for (; j + 7 < cnt; j += 8){
            EDGE(0, d0, ax0, ay0); EDGE(1, d1, ax1, ay1);
            EDGE(2, d0, ax0, ay0); EDGE(3, d1, ax1, ay1);
            EDGE(4, d0, ax0, ay0); EDGE(5, d1, ax1, ay1);
            EDGE(6, d0, ax0, ay0); EDGE(7, d1, ax1, ay1);
        }
        for (; j < cnt; ++j){
            EDGE(0, d0, ax0, ay0);
        }
    }
    float dsum = d0 + d1;
    float r = (dsum > 0.f) ? 1.f/dsum : 0.f;
    __hip_bfloat162 o2;
    o2.x = __float2bfloat16((ax0 + ax1)*r);
    o2.y = __float2bfloat16((ay0 + ay1)*r);
    ((__hip_bfloat162*)(a + (size_t)wid*D))[lane] = o2;
}

extern "C" void kernel_launch(void* const* d_in, const int* in_sizes, int n_in,
                              void* d_out, int out_size, void* d_ws, size_t ws_size,
                              hipStream_t stream){
    const float* h    = (const float*)d_in[0];
    const int*   src  = (const int*)  d_in[1];
    const int*   dst  = (const int*)  d_in[2];
    const float* Wq   = (const float*)d_in[3];
    const float* Wk   = (const float*)d_in[4];
    const float* Wv   = (const float*)d_in[5];
    const float* Wo   = (const float*)d_in[6];
    const float* ln1g = (const float*)d_in[7];
    const float* ln1b = (const float*)d_in[8];
    const float* ln2g = (const float*)d_in[9];
    const float* ln2b = (const float*)d_in[10];
    const float* W1   = (const float*)d_in[11];
    const float* b1   = (const float*)d_in[12];
    const float* W2   = (const float*)d_in[13];
    const float* b2   = (const float*)d_in[14];
    float* out = (float*)d_out;

    const int N = in_sizes[0] / D;
    const int E = in_sizes[1];

    char* ws = (char*)d_ws;
    size_t o = 0;
    const size_t row_bf = align256((size_t)N * D * sizeof(__hip_bfloat16));    // 12.8 MB
    const size_t kv_q   = align256((size_t)N * 256);                           // 12.8 MB
    const size_t t1_bf  = align256((size_t)N * FFD * sizeof(__hip_bfloat16));  // 51.2 MB

    __hip_bfloat16* qb  = (__hip_bfloat16*)(ws + o); o += row_bf;
    unsigned char* kvq  = (unsigned char*)(ws + o); o += kv_q;
    __hip_bfloat16* ab  = (__hip_bfloat16*)(ws + o); o += row_bf;
    __hip_bfloat16* hb  = (__hip_bfloat16*)(ws + o); o += row_bf;
    __hip_bfloat16* h1b = hb;   // overlays hb after QKV GEMM
    __hip_bfloat16* t1b = (__hip_bfloat16*)(ws + o); o += t1_bf;
    __hip_bfloat16* Wqkvt = (__hip_bfloat16*)(ws + o); o += align256(384*128*2);
    __hip_bfloat16* W1t   = (__hip_bfloat16*)(ws + o); o += align256(512*128*2);
    __hip_bfloat16* W2t   = (__hip_bfloat16*)(ws + o); o += align256(128*512*2);
    __hip_bfloat16* Wot   = (__hip_bfloat16*)(ws + o); o += align256(128*128*2);
    int* cnt   = (int*)(ws + o); o += align256((size_t)N*4);
    int* cur   = (int*)(ws + o); o += align256((size_t)N*4);
    int* offp  = (int*)(ws + o); o += align256((size_t)(N+1)*4);
    int* bsum  = (int*)(ws + o); o += align256(1024*4);
    int* ebase = (int*)(ws + o); o += align256(1024*4);
    int* csr   = (int*)(ws + o); o += align256((size_t)E*4);

    const int NB = (N + 255)/256;   // 196

    // --- prep + CSR build ---
    (void)hipMemsetAsync(cnt, 0, (size_t)N*4, stream);
    k_count<<<min((E + 255)/256, 4096), 256, 0, stream>>>(dst, E, cnt);
    k_cast<<<(N*D/4 + 255)/256, 256, 0, stream>>>(h, hb, N*D/4);
    k_prep_all<<<dim3(64, 6), 256, 0, stream>>>(Wq, Wk, Wv, Wo, W1, W2,
                                                Wqkvt, Wot, W1t, W2t);
    k_bsum <<<NB, 256, 0, stream>>>(cnt, N, bsum);
    k_scanb<<<1, 1024, 0, stream>>>(bsum, NB, ebase, offp, N);
    k_off  <<<NB, 256, 0, stream>>>(cnt, N, ebase, offp, cur);
    k_scatter<<<1024, 256, 0, stream>>>(src, dst, E, cur, csr, N);

    int mb = (N + BM - 1)/BM;            // 391
    int mb_pad = ((mb + 7)/8)*8;         // 392

    // --- QKV projection (q bf16 + kv fp8 epilogue) ---
    k_gemm<1><<<dim3(3, mb_pad), 256, 0, stream>>>(hb, Wqkvt, N, 384, 128,
        nullptr, 0, nullptr, qb, kvq, nullptr, nullptr, nullptr, nullptr, nullptr, nullptr);

    // --- sparse attention ---
    k_attn<<<(N*64 + 255)/256, 256, 0, stream>>>(qb, (const unsigned*)kvq, offp, csr, ab, N);

    // --- Wo projection + residual(h, f32) + LN1 -> h1b (bf16) ---
    k_gemm<2><<<dim3(1, mb_pad), 256, 0, stream>>>(ab, Wot, N, 128, 128,
        nullptr, 0, nullptr, nullptr, nullptr, h, nullptr, ln1g, ln1b, nullptr, h1b);

    // --- FFN1: relu(h1b @ W1 + b1) -> t1b ---
    k_gemm<0><<<dim3(4, mb_pad), 256, 0, stream>>>(h1b, W1t, N, 512, 128,
        b1, 1, t1b, nullptr, nullptr, nullptr, nullptr, nullptr, nullptr, nullptr, nullptr);

    // --- FFN2 + residual(h1b, bf16) + LN2 -> out (f32) ---
    k_gemm<3><<<dim3(1, mb_pad), 256, 0, stream>>>(t1b, W2t, N, 128, 512,
        b2, 0, nullptr, nullptr, nullptr, nullptr, h1b, ln2g, ln2b, out, nullptr);
}